// Round 3
// baseline (1141.506 us; speedup 1.0000x reference)
//
#include <hip/hip_runtime.h>

#define NN 100000
#define EE 1600000
#define HH 128
#define GG 64
#define LL 3
#define BN_EPS 1e-5f
#define SCAN_B 512
#define NBLK 196            // ceil(NN / SCAN_B)

// ---- int64-vs-int32 detection: odd int32 slots all zero <=> int64 --------
__global__ __launch_bounds__(256) void k_idet(const int* __restrict__ ei,
                                              int* __restrict__ flag) {
    __shared__ int bad;
    if (threadIdx.x == 0) bad = 0;
    __syncthreads();
    int nz = 0;
    for (int j = 0; j < 16; j++) {
        int i = threadIdx.x * 16 + j;          // sample 4096 edges
        if (ei[2 * i + 1] != 0) nz = 1;
    }
    if (nz) atomicOr(&bad, 1);
    __syncthreads();
    if (threadIdx.x == 0) *flag = bad ? 0 : 1; // 1 = int64 layout
}

__device__ __forceinline__ int geti(const int* __restrict__ p, int i, int f) {
    return f ? p[2 * i] : p[i];
}

// ---- CSR build: count ----------------------------------------------------
__global__ void k_count(const int* __restrict__ ei, int* __restrict__ cnt,
                        const int* __restrict__ flag) {
    int e = blockIdx.x * 256 + threadIdx.x;
    int f = *flag;
    if (e < EE) atomicAdd(&cnt[geti(ei, EE + e, f)], 1);
}

// ---- scan pass 1: per-block inclusive scan -------------------------------
__global__ __launch_bounds__(SCAN_B) void k_scan1(const int* __restrict__ cnt,
        int* __restrict__ incl, int* __restrict__ blksum) {
    __shared__ int sd[SCAN_B];
    int t = threadIdx.x, i = blockIdx.x * SCAN_B + t;
    sd[t] = i < NN ? cnt[i] : 0;
    __syncthreads();
    for (int off = 1; off < SCAN_B; off <<= 1) {
        int y = t >= off ? sd[t - off] : 0;
        __syncthreads();
        sd[t] += y;
        __syncthreads();
    }
    if (i < NN) incl[i] = sd[t];
    if (t == SCAN_B - 1) blksum[blockIdx.x] = sd[t];
}

// ---- scan pass 2: scan the block sums (single block, in place) -----------
__global__ __launch_bounds__(256) void k_scan2(int* __restrict__ blksum) {
    __shared__ int sd[256];
    int t = threadIdx.x;
    sd[t] = t < NBLK ? blksum[t] : 0;
    __syncthreads();
    for (int off = 1; off < 256; off <<= 1) {
        int y = t >= off ? sd[t - off] : 0;
        __syncthreads();
        sd[t] += y;
        __syncthreads();
    }
    if (t < NBLK) blksum[t] = sd[t];
}

// ---- scan pass 3: offsets/cursor/dinv + folded BN + pool init ------------
__global__ void k_scan3(const int* __restrict__ cnt, int* __restrict__ offs,
        const int* __restrict__ blksum, int* __restrict__ cursor,
        float* __restrict__ dinv, float* __restrict__ bnA, float* __restrict__ bnB,
        const float* __restrict__ conv_b, const float* __restrict__ g,
        const float* __restrict__ be, const float* __restrict__ mn,
        const float* __restrict__ vr, float* __restrict__ gsum,
        float* __restrict__ gcnt) {
    int i = blockIdx.x * 256 + threadIdx.x;
    if (i < NN) {
        int b = i / SCAN_B;
        int add = b > 0 ? blksum[b - 1] : 0;
        int c = cnt[i];
        int ex = offs[i] + add - c;            // exclusive prefix
        offs[i] = ex;
        cursor[i] = ex;
        dinv[i] = rsqrtf(1.0f + (float)c);     // +1 = self loop
    }
    if (i < LL * HH) {
        float A = g[i] * rsqrtf(vr[i] + BN_EPS);
        bnA[i] = A;
        bnB[i] = (conv_b[i] - mn[i]) * A + be[i];
    }
    if (i < GG * HH) gsum[i] = 0.f;
    if (i < GG) gcnt[i] = 0.f;
}

// ---- CSR build: fill (counting sort by dst) ------------------------------
__global__ void k_fill(const int* __restrict__ ei, int* __restrict__ cursor,
                       int* __restrict__ csr, const int* __restrict__ flag) {
    int e = blockIdx.x * 256 + threadIdx.x;
    int f = *flag;
    if (e < EE) {
        int dst = geti(ei, EE + e, f);
        int pos = atomicAdd(&cursor[dst], 1);
        csr[pos] = geti(ei, e, f);
    }
}

// ---- transpose weights: cwT[l][k][c] = conv_w[l][c][k]; n1T[k][c] --------
__global__ void k_prep(const float* __restrict__ conv_w,
                       const float* __restrict__ nw1,
                       float* __restrict__ cwT, float* __restrict__ n1T) {
    int i = blockIdx.x * 256 + threadIdx.x;
    if (i < LL * HH * HH) {
        int l = i >> 14, r = i & 16383;        // r = k*128 + c (dst layout)
        int k = r >> 7, c = r & 127;
        cwT[i] = conv_w[(l << 14) + c * HH + k];
    }
    if (i < 64 * HH) {                          // i = k*64 + c
        int k = i >> 6, c = i & 63;
        n1T[i] = nw1[c * HH + k];
    }
}

// ---- f32 tiled GEMM: out[r][c] = sum_k in[r][k] * Wt[k][c] (+bias,relu) --
// block = 256 thr, tile 64 rows x NC cols; input rows staged in LDS.
template<int NC>
__global__ __launch_bounds__(256) void k_gemm(const float* __restrict__ in,
        const float* __restrict__ Wt, const float* __restrict__ bias,
        float* __restrict__ out, int do_relu) {
    __shared__ float lin[64][HH];
    int t = threadIdx.x;
    int r0 = blockIdx.x * 64;
#pragma unroll
    for (int j = 0; j < 8; j++) {
        int fi = t + 256 * j;                  // float4 index 0..2047
        int row = fi >> 5, k4 = fi & 31;
        int gr = r0 + row;
        if (gr >= NN) gr = NN - 1;             // clamp (stores guarded)
        float4 v = ((const float4*)(in + (size_t)gr * HH))[k4];
        ((float4*)&lin[row][0])[k4] = v;
    }
    __syncthreads();
    constexpr int TX = NC / 4;                 // lanes covering cols
    constexpr int RG = 64 / (256 / TX);        // rows per thread
    int tx = t % TX, ty = t / TX;
    int rbase = ty * RG;
    float4 acc[RG];
#pragma unroll
    for (int i = 0; i < RG; i++) acc[i] = make_float4(0.f, 0.f, 0.f, 0.f);
    for (int k = 0; k < HH; k++) {
        float4 w = ((const float4*)(Wt + k * NC))[tx];
#pragma unroll
        for (int i = 0; i < RG; i++) {
            float a = lin[rbase + i][k];
            acc[i].x = fmaf(a, w.x, acc[i].x);
            acc[i].y = fmaf(a, w.y, acc[i].y);
            acc[i].z = fmaf(a, w.z, acc[i].z);
            acc[i].w = fmaf(a, w.w, acc[i].w);
        }
    }
    float4 bv = bias ? ((const float4*)bias)[tx] : make_float4(0.f, 0.f, 0.f, 0.f);
#pragma unroll
    for (int i = 0; i < RG; i++) {
        int gr = r0 + rbase + i;
        if (gr < NN) {
            float4 v = acc[i];
            v.x += bv.x; v.y += bv.y; v.z += bv.z; v.w += bv.w;
            if (do_relu) {
                v.x = fmaxf(v.x, 0.f); v.y = fmaxf(v.y, 0.f);
                v.z = fmaxf(v.z, 0.f); v.w = fmaxf(v.w, 0.f);
            }
            ((float4*)(out + (size_t)gr * NC))[tx] = v;
        }
    }
}

// ---- fused gather segment-reduce + self-loop + BN + ReLU (f32) -----------
// one wave per node; lane covers channels {2*lane, 2*lane+1}
__global__ __launch_bounds__(256) void k_aggr(const float* __restrict__ t,
        const int* __restrict__ csr, const int* __restrict__ offs,
        const int* __restrict__ cnt, const float* __restrict__ dinv,
        const float* __restrict__ bnA, const float* __restrict__ bnB,
        float* __restrict__ hout) {
    int wave = threadIdx.x >> 6, lane = threadIdx.x & 63;
    int node = blockIdx.x * 4 + wave;
    if (node >= NN) return;
    int base = offs[node], ne = cnt[node];
    float dd = dinv[node];
    float2 self = ((const float2*)(t + (size_t)node * HH))[lane];
    float d2 = dd * dd;
    float a0 = self.x * d2, a1 = self.y * d2;
    int sn = 0; float dn = 0.f; float2 vn = make_float2(0.f, 0.f);
    if (ne > 0) {                               // software pipeline depth 1
        sn = csr[base];
        dn = dinv[sn];
        vn = ((const float2*)(t + (size_t)sn * HH))[lane];
    }
    for (int k = 0; k < ne; k++) {
        float2 v = vn; float dc = dn;
        if (k + 1 < ne) {
            sn = csr[base + k + 1];
            dn = dinv[sn];
            vn = ((const float2*)(t + (size_t)sn * HH))[lane];
        }
        float nrm = dc * dd;
        a0 = fmaf(v.x, nrm, a0);
        a1 = fmaf(v.y, nrm, a1);
    }
    float2 Av = ((const float2*)bnA)[lane];
    float2 Bv = ((const float2*)bnB)[lane];
    float r0 = fmaxf(fmaf(a0, Av.x, Bv.x), 0.f);
    float r1 = fmaxf(fmaf(a1, Av.y, Bv.y), 0.f);
    ((float2*)(hout + (size_t)node * HH))[lane] = make_float2(r0, r1);
}

// ---- node head stage 2: y2 = y1 @ w2^T + b2 (64 -> 2) --------------------
__global__ __launch_bounds__(256) void k_nodey2(const float* __restrict__ y1,
        const float* __restrict__ w2, const float* __restrict__ b2v,
        float* __restrict__ out) {
    int wave = threadIdx.x >> 6, lane = threadIdx.x & 63;
    int node = blockIdx.x * 4 + wave;
    if (node >= NN) return;
    float y = y1[(size_t)node * 64 + lane];
    float v0 = y * w2[lane];
    float v1 = y * w2[64 + lane];
#pragma unroll
    for (int off = 32; off; off >>= 1) {
        v0 += __shfl_xor(v0, off);
        v1 += __shfl_xor(v1, off);
    }
    if (lane == 0) {
        out[(size_t)node * 2]     = v0 + b2v[0];
        out[(size_t)node * 2 + 1] = v1 + b2v[1];
    }
}

// ---- graph pooling: sorted-run partial sums, few atomics -----------------
#define PN 256
__global__ __launch_bounds__(128) void k_pool(const float* __restrict__ hb,
        const int* __restrict__ batch, float* __restrict__ gsum,
        float* __restrict__ gcnt, const int* __restrict__ flag) {
    int j = threadIdx.x;
    int f = *flag;
    int s0 = blockIdx.x * PN;
    int e0 = s0 + PN < NN ? s0 + PN : NN;
    int cur = geti(batch, s0, f);
    float acc = 0.f, cn = 0.f;
    for (int n = s0; n < e0; n++) {
        int g = geti(batch, n, f);
        if (g != cur) {
            atomicAdd(&gsum[cur * HH + j], acc);
            if (j == 0) atomicAdd(&gcnt[cur], cn);
            acc = 0.f; cn = 0.f; cur = g;
        }
        acc += hb[(size_t)n * HH + j];
        cn += 1.f;
    }
    atomicAdd(&gsum[cur * HH + j], acc);
    if (j == 0) atomicAdd(&gcnt[cur], cn);
}

// ---- graph head: one block per graph -------------------------------------
__global__ __launch_bounds__(64) void k_ghead(const float* __restrict__ gsum,
        const float* __restrict__ gcnt, const float* __restrict__ w1,
        const float* __restrict__ b1, const float* __restrict__ w2,
        const float* __restrict__ b2v, float* __restrict__ out) {
    __shared__ float emb[HH];
    int g = blockIdx.x, lane = threadIdx.x;
    float cn = gcnt[g];
    cn = cn > 1.f ? cn : 1.f;
    float inv = 1.f / cn;
    emb[lane] = gsum[g * HH + lane] * inv;
    emb[lane + 64] = gsum[g * HH + 64 + lane] * inv;
    __syncthreads();
    float acc = b1[lane];
    for (int k = 0; k < HH; k++) acc = fmaf(emb[k], w1[lane * HH + k], acc);
    float y = fmaxf(acc, 0.f);
    float v0 = y * w2[lane];
    float v1 = y * w2[64 + lane];
#pragma unroll
    for (int off = 32; off; off >>= 1) {
        v0 += __shfl_xor(v0, off);
        v1 += __shfl_xor(v1, off);
    }
    if (lane == 0) {
        out[(size_t)NN * 2 + g * 2]     = v0 + b2v[0];
        out[(size_t)NN * 2 + g * 2 + 1] = v1 + b2v[1];
    }
}

extern "C" void kernel_launch(void* const* d_in, const int* in_sizes, int n_in,
                              void* d_out, int out_size, void* d_ws, size_t ws_size,
                              hipStream_t stream) {
    const float* x      = (const float*)d_in[0];
    const int*   ei     = (const int*)d_in[1];
    const int*   batch  = (const int*)d_in[2];
    const float* conv_w = (const float*)d_in[3];
    const float* conv_b = (const float*)d_in[4];
    const float* bn_g   = (const float*)d_in[5];
    const float* bn_b   = (const float*)d_in[6];
    const float* bn_m   = (const float*)d_in[7];
    const float* bn_v   = (const float*)d_in[8];
    const float* nw1    = (const float*)d_in[9];
    const float* nb1    = (const float*)d_in[10];
    const float* nw2    = (const float*)d_in[11];
    const float* nb2    = (const float*)d_in[12];
    const float* gw1    = (const float*)d_in[13];
    const float* gb1    = (const float*)d_in[14];
    const float* gw2    = (const float*)d_in[15];
    const float* gb2    = (const float*)d_in[16];
    float* out = (float*)d_out;

    char* ws = (char*)d_ws;
    size_t off = 0;
    auto alloc = [&](size_t bytes) -> void* {
        void* p = ws + off;
        off += (bytes + 255) & ~(size_t)255;
        return p;
    };
    float* tA     = (float*)alloc((size_t)NN * HH * 4);  // 51.2 MB
    float* tB     = (float*)alloc((size_t)NN * HH * 4);  // 51.2 MB
    int*   csr    = (int*)  alloc((size_t)EE * 4);       // 6.4 MB
    int*   offs   = (int*)  alloc((size_t)NN * 4);
    int*   cnt    = (int*)  alloc((size_t)NN * 4);
    int*   cursor = (int*)  alloc((size_t)NN * 4);
    float* dinv   = (float*)alloc((size_t)NN * 4);
    int*   blksum = (int*)  alloc((size_t)NBLK * 4);
    float* bnA    = (float*)alloc((size_t)LL * HH * 4);
    float* bnB    = (float*)alloc((size_t)LL * HH * 4);
    float* gsum   = (float*)alloc((size_t)GG * HH * 4);
    float* gcnt   = (float*)alloc((size_t)GG * 4);
    float* cwT    = (float*)alloc((size_t)LL * HH * HH * 4);
    float* n1T    = (float*)alloc((size_t)64 * HH * 4);
    int*   flag   = (int*)  alloc(256);

    // int-width detect + CSR build + dinv + folded BN + weight transpose
    k_idet<<<1, 256, 0, stream>>>(ei, flag);
    hipMemsetAsync(cnt, 0, (size_t)NN * 4, stream);
    k_count<<<(EE + 255) / 256, 256, 0, stream>>>(ei, cnt, flag);
    k_scan1<<<NBLK, SCAN_B, 0, stream>>>(cnt, offs, blksum);
    k_scan2<<<1, 256, 0, stream>>>(blksum);
    k_scan3<<<(NN + 255) / 256, 256, 0, stream>>>(cnt, offs, blksum, cursor,
            dinv, bnA, bnB, conv_b, bn_g, bn_b, bn_m, bn_v, gsum, gcnt);
    k_fill<<<(EE + 255) / 256, 256, 0, stream>>>(ei, cursor, csr, flag);
    k_prep<<<(LL * HH * HH + 255) / 256, 256, 0, stream>>>(conv_w, nw1, cwT, n1T);

    // 3 GCN layers: gemm(h -> t), fused aggregate+BN+ReLU (t -> h)
    for (int l = 0; l < LL; l++) {
        const float* hin = (l == 0) ? x : tB;
        k_gemm<HH><<<(NN + 63) / 64, 256, 0, stream>>>(hin, cwT + (size_t)l * HH * HH,
                                                       nullptr, tA, 0);
        k_aggr<<<(NN + 3) / 4, 256, 0, stream>>>(tA, csr, offs, cnt, dinv,
                                                 bnA + l * HH, bnB + l * HH, tB);
    }

    // node head: y1 = relu(h @ nw1^T + b1), then 64->2 reduce
    k_gemm<64><<<(NN + 63) / 64, 256, 0, stream>>>(tB, n1T, nb1, tA, 1);
    k_nodey2<<<(NN + 3) / 4, 256, 0, stream>>>(tA, nw2, nb2, out);

    // graph head
    k_pool<<<(NN + PN - 1) / PN, 128, 0, stream>>>(tB, batch, gsum, gcnt, flag);
    k_ghead<<<GG, 64, 0, stream>>>(gsum, gcnt, gw1, gb1, gw2, gb2, out);
}

// Round 4
// 1032.563 us; speedup vs baseline: 1.1055x; 1.1055x over previous
//
#include <hip/hip_runtime.h>
#include <hip/hip_bf16.h>

#define NN 100000
#define EE 1600000
#define HH 128
#define GG 64
#define LL 3
#define BN_EPS 1e-5f
#define SCAN_B 512
#define NBLK 196            // ceil(NN / SCAN_B)

typedef __hip_bfloat16 bf16;

__device__ __forceinline__ float lo16(unsigned v) { return __uint_as_float(v << 16); }
__device__ __forceinline__ float hi16(unsigned v) { return __uint_as_float(v & 0xffff0000u); }
__device__ __forceinline__ unsigned pack2(float a, float b) {
    bf16 ha = __float2bfloat16(a), hb = __float2bfloat16(b);
    unsigned short ua = *(unsigned short*)&ha, ub = *(unsigned short*)&hb;
    return (unsigned)ua | ((unsigned)ub << 16);
}

// ---- int64-vs-int32 detection: odd int32 slots all zero <=> int64 --------
__global__ __launch_bounds__(256) void k_idet(const int* __restrict__ ei,
                                              int* __restrict__ flag) {
    __shared__ int bad;
    if (threadIdx.x == 0) bad = 0;
    __syncthreads();
    int nz = 0;
    for (int j = 0; j < 16; j++) {
        int i = threadIdx.x * 16 + j;          // sample 4096 edges
        if (ei[2 * i + 1] != 0) nz = 1;
    }
    if (nz) atomicOr(&bad, 1);
    __syncthreads();
    if (threadIdx.x == 0) *flag = bad ? 0 : 1; // 1 = int64 layout
}

__device__ __forceinline__ int geti(const int* __restrict__ p, int i, int f) {
    return f ? p[2 * i] : p[i];
}

// ---- CSR build: count ----------------------------------------------------
__global__ void k_count(const int* __restrict__ ei, int* __restrict__ cnt,
                        const int* __restrict__ flag) {
    int e = blockIdx.x * 256 + threadIdx.x;
    int f = *flag;
    if (e < EE) atomicAdd(&cnt[geti(ei, EE + e, f)], 1);
}

// ---- scan pass 1: per-block inclusive scan -------------------------------
__global__ __launch_bounds__(SCAN_B) void k_scan1(const int* __restrict__ cnt,
        int* __restrict__ incl, int* __restrict__ blksum) {
    __shared__ int sd[SCAN_B];
    int t = threadIdx.x, i = blockIdx.x * SCAN_B + t;
    sd[t] = i < NN ? cnt[i] : 0;
    __syncthreads();
    for (int off = 1; off < SCAN_B; off <<= 1) {
        int y = t >= off ? sd[t - off] : 0;
        __syncthreads();
        sd[t] += y;
        __syncthreads();
    }
    if (i < NN) incl[i] = sd[t];
    if (t == SCAN_B - 1) blksum[blockIdx.x] = sd[t];
}

// ---- scan pass 2: scan the block sums (single block, in place) -----------
__global__ __launch_bounds__(256) void k_scan2(int* __restrict__ blksum) {
    __shared__ int sd[256];
    int t = threadIdx.x;
    sd[t] = t < NBLK ? blksum[t] : 0;
    __syncthreads();
    for (int off = 1; off < 256; off <<= 1) {
        int y = t >= off ? sd[t - off] : 0;
        __syncthreads();
        sd[t] += y;
        __syncthreads();
    }
    if (t < NBLK) blksum[t] = sd[t];
}

// ---- scan pass 3: offsets/cursor/dinv + folded BN + pool init ------------
__global__ void k_scan3(const int* __restrict__ cnt, int* __restrict__ offs,
        const int* __restrict__ blksum, int* __restrict__ cursor,
        float* __restrict__ dinv, float* __restrict__ bnA, float* __restrict__ bnB,
        const float* __restrict__ conv_b, const float* __restrict__ g,
        const float* __restrict__ be, const float* __restrict__ mn,
        const float* __restrict__ vr, float* __restrict__ gsum,
        float* __restrict__ gcnt) {
    int i = blockIdx.x * 256 + threadIdx.x;
    if (i < NN) {
        int b = i / SCAN_B;
        int add = b > 0 ? blksum[b - 1] : 0;
        int c = cnt[i];
        int ex = offs[i] + add - c;            // exclusive prefix
        offs[i] = ex;
        cursor[i] = ex;
        dinv[i] = rsqrtf(1.0f + (float)c);     // +1 = self loop
    }
    if (i < LL * HH) {
        float A = g[i] * rsqrtf(vr[i] + BN_EPS);
        bnA[i] = A;
        bnB[i] = (conv_b[i] - mn[i]) * A + be[i];
    }
    if (i < GG * HH) gsum[i] = 0.f;
    if (i < GG) gcnt[i] = 0.f;
}

// ---- CSR build: fill (counting sort by dst) ------------------------------
__global__ void k_fill(const int* __restrict__ ei, int* __restrict__ cursor,
                       int* __restrict__ csr, const int* __restrict__ flag) {
    int e = blockIdx.x * 256 + threadIdx.x;
    int f = *flag;
    if (e < EE) {
        int dst = geti(ei, EE + e, f);
        int pos = atomicAdd(&cursor[dst], 1);
        csr[pos] = geti(ei, e, f);
    }
}

// ---- transpose weights: cwT[l][k][c] = conv_w[l][c][k]; n1T[k][c] --------
__global__ void k_prep(const float* __restrict__ conv_w,
                       const float* __restrict__ nw1,
                       float* __restrict__ cwT, float* __restrict__ n1T) {
    int i = blockIdx.x * 256 + threadIdx.x;
    if (i < LL * HH * HH) {
        int l = i >> 14, r = i & 16383;        // r = k*128 + c (dst layout)
        int k = r >> 7, c = r & 127;
        cwT[i] = conv_w[(l << 14) + c * HH + k];
    }
    if (i < 64 * HH) {                          // i = k*64 + c
        int k = i >> 6, c = i & 63;
        n1T[i] = nw1[c * HH + k];
    }
}

// ---- f32 tiled GEMM: out[r][c] = sum_k in[r][k] * Wt[k][c] (+bias,relu) --
// block = 256 thr, tile 64 rows x NC cols; input rows staged in LDS.
// outF (f32, row stride NC) and/or out2 (packed bf16 pairs, row stride NC/2)
template<int NC>
__global__ __launch_bounds__(256) void k_gemm(const float* __restrict__ in,
        const float* __restrict__ Wt, const float* __restrict__ bias,
        float* __restrict__ outF, unsigned* __restrict__ out2, int do_relu) {
    __shared__ float lin[64][HH];
    int t = threadIdx.x;
    int r0 = blockIdx.x * 64;
#pragma unroll
    for (int j = 0; j < 8; j++) {
        int fi = t + 256 * j;                  // float4 index 0..2047
        int row = fi >> 5, k4 = fi & 31;
        int gr = r0 + row;
        if (gr >= NN) gr = NN - 1;             // clamp (stores guarded)
        float4 v = ((const float4*)(in + (size_t)gr * HH))[k4];
        ((float4*)&lin[row][0])[k4] = v;
    }
    __syncthreads();
    constexpr int TX = NC / 4;                 // lanes covering cols
    constexpr int RG = 64 / (256 / TX);        // rows per thread
    int tx = t % TX, ty = t / TX;
    int rbase = ty * RG;
    float4 acc[RG];
#pragma unroll
    for (int i = 0; i < RG; i++) acc[i] = make_float4(0.f, 0.f, 0.f, 0.f);
    for (int k = 0; k < HH; k++) {
        float4 w = ((const float4*)(Wt + k * NC))[tx];
#pragma unroll
        for (int i = 0; i < RG; i++) {
            float a = lin[rbase + i][k];
            acc[i].x = fmaf(a, w.x, acc[i].x);
            acc[i].y = fmaf(a, w.y, acc[i].y);
            acc[i].z = fmaf(a, w.z, acc[i].z);
            acc[i].w = fmaf(a, w.w, acc[i].w);
        }
    }
    float4 bv = bias ? ((const float4*)bias)[tx] : make_float4(0.f, 0.f, 0.f, 0.f);
#pragma unroll
    for (int i = 0; i < RG; i++) {
        int gr = r0 + rbase + i;
        if (gr < NN) {
            float4 v = acc[i];
            v.x += bv.x; v.y += bv.y; v.z += bv.z; v.w += bv.w;
            if (do_relu) {
                v.x = fmaxf(v.x, 0.f); v.y = fmaxf(v.y, 0.f);
                v.z = fmaxf(v.z, 0.f); v.w = fmaxf(v.w, 0.f);
            }
            if (outF) ((float4*)(outF + (size_t)gr * NC))[tx] = v;
            if (out2)
                ((uint2*)(out2 + (size_t)gr * (NC / 2)))[tx] =
                    make_uint2(pack2(v.x, v.y), pack2(v.z, v.w));
        }
    }
}

// ---- fused gather segment-reduce + self-loop + BN + ReLU -----------------
// one wave per node; lane covers channels {2*lane, 2*lane+1}; t in packed
// bf16 pairs (256 B/row gather), f32 accumulate, depth-2 pipeline.
__global__ __launch_bounds__(256) void k_aggr(const unsigned* __restrict__ tH,
        const int* __restrict__ csr, const int* __restrict__ offs,
        const int* __restrict__ cnt, const float* __restrict__ dinv,
        const float* __restrict__ bnA, const float* __restrict__ bnB,
        float* __restrict__ hout) {
    int wave = threadIdx.x >> 6, lane = threadIdx.x & 63;
    int node = blockIdx.x * 4 + wave;
    if (node >= NN) return;
    int base = offs[node], ne = cnt[node];
    float dd = dinv[node];
    unsigned sv = tH[(size_t)node * 64 + lane];
    float d2 = dd * dd;
    float a0 = lo16(sv) * d2, a1 = hi16(sv) * d2;
    int sB = 0; float dA = 0.f, dB = 0.f; unsigned vA = 0, vB = 0;
    if (ne > 0) {
        int sA = csr[base];
        dA = dinv[sA];
        vA = tH[(size_t)sA * 64 + lane];
    }
    if (ne > 1) {
        sB = csr[base + 1];
        dB = dinv[sB];
        vB = tH[(size_t)sB * 64 + lane];
    }
    for (int k = 0; k < ne; k++) {
        float dc = dA; unsigned vc = vA;
        dA = dB; vA = vB;
        if (k + 2 < ne) {
            sB = csr[base + k + 2];
            dB = dinv[sB];
            vB = tH[(size_t)sB * 64 + lane];
        }
        float nrm = dc * dd;
        a0 = fmaf(lo16(vc), nrm, a0);
        a1 = fmaf(hi16(vc), nrm, a1);
    }
    float2 Av = ((const float2*)bnA)[lane];
    float2 Bv = ((const float2*)bnB)[lane];
    float r0 = fmaxf(fmaf(a0, Av.x, Bv.x), 0.f);
    float r1 = fmaxf(fmaf(a1, Av.y, Bv.y), 0.f);
    ((float2*)(hout + (size_t)node * HH))[lane] = make_float2(r0, r1);
}

// ---- node head stage 2: y2 = y1 @ w2^T + b2 (64 -> 2) --------------------
__global__ __launch_bounds__(256) void k_nodey2(const float* __restrict__ y1,
        const float* __restrict__ w2, const float* __restrict__ b2v,
        float* __restrict__ out) {
    int wave = threadIdx.x >> 6, lane = threadIdx.x & 63;
    int node = blockIdx.x * 4 + wave;
    if (node >= NN) return;
    float y = y1[(size_t)node * 64 + lane];
    float v0 = y * w2[lane];
    float v1 = y * w2[64 + lane];
#pragma unroll
    for (int off = 32; off; off >>= 1) {
        v0 += __shfl_xor(v0, off);
        v1 += __shfl_xor(v1, off);
    }
    if (lane == 0) {
        out[(size_t)node * 2]     = v0 + b2v[0];
        out[(size_t)node * 2 + 1] = v1 + b2v[1];
    }
}

// ---- graph pooling: 1 wave per 32-node chunk, run-flush atomics ----------
#define PN 32
__global__ __launch_bounds__(64) void k_pool(const float* __restrict__ hb,
        const int* __restrict__ batch, float* __restrict__ gsum,
        float* __restrict__ gcnt, const int* __restrict__ flag) {
    int lane = threadIdx.x;
    int f = *flag;
    int s0 = blockIdx.x * PN;
    int e0 = s0 + PN < NN ? s0 + PN : NN;
    int cur = geti(batch, s0, f);
    float a0 = 0.f, a1 = 0.f, cn = 0.f;
    for (int n = s0; n < e0; n++) {
        int g = geti(batch, n, f);
        if (g != cur) {                        // wave-uniform branch
            atomicAdd(&gsum[cur * HH + 2 * lane], a0);
            atomicAdd(&gsum[cur * HH + 2 * lane + 1], a1);
            if (lane == 0) atomicAdd(&gcnt[cur], cn);
            a0 = a1 = cn = 0.f; cur = g;
        }
        float2 v = ((const float2*)(hb + (size_t)n * HH))[lane];
        a0 += v.x; a1 += v.y; cn += 1.f;
    }
    atomicAdd(&gsum[cur * HH + 2 * lane], a0);
    atomicAdd(&gsum[cur * HH + 2 * lane + 1], a1);
    if (lane == 0) atomicAdd(&gcnt[cur], cn);
}

// ---- graph head: one block per graph -------------------------------------
__global__ __launch_bounds__(64) void k_ghead(const float* __restrict__ gsum,
        const float* __restrict__ gcnt, const float* __restrict__ w1,
        const float* __restrict__ b1, const float* __restrict__ w2,
        const float* __restrict__ b2v, float* __restrict__ out) {
    __shared__ float emb[HH];
    int g = blockIdx.x, lane = threadIdx.x;
    float cn = gcnt[g];
    cn = cn > 1.f ? cn : 1.f;
    float inv = 1.f / cn;
    emb[lane] = gsum[g * HH + lane] * inv;
    emb[lane + 64] = gsum[g * HH + 64 + lane] * inv;
    __syncthreads();
    float acc = b1[lane];
    for (int k = 0; k < HH; k++) acc = fmaf(emb[k], w1[lane * HH + k], acc);
    float y = fmaxf(acc, 0.f);
    float v0 = y * w2[lane];
    float v1 = y * w2[64 + lane];
#pragma unroll
    for (int off = 32; off; off >>= 1) {
        v0 += __shfl_xor(v0, off);
        v1 += __shfl_xor(v1, off);
    }
    if (lane == 0) {
        out[(size_t)NN * 2 + g * 2]     = v0 + b2v[0];
        out[(size_t)NN * 2 + g * 2 + 1] = v1 + b2v[1];
    }
}

extern "C" void kernel_launch(void* const* d_in, const int* in_sizes, int n_in,
                              void* d_out, int out_size, void* d_ws, size_t ws_size,
                              hipStream_t stream) {
    const float* x      = (const float*)d_in[0];
    const int*   ei     = (const int*)d_in[1];
    const int*   batch  = (const int*)d_in[2];
    const float* conv_w = (const float*)d_in[3];
    const float* conv_b = (const float*)d_in[4];
    const float* bn_g   = (const float*)d_in[5];
    const float* bn_b   = (const float*)d_in[6];
    const float* bn_m   = (const float*)d_in[7];
    const float* bn_v   = (const float*)d_in[8];
    const float* nw1    = (const float*)d_in[9];
    const float* nb1    = (const float*)d_in[10];
    const float* nw2    = (const float*)d_in[11];
    const float* nb2    = (const float*)d_in[12];
    const float* gw1    = (const float*)d_in[13];
    const float* gb1    = (const float*)d_in[14];
    const float* gw2    = (const float*)d_in[15];
    const float* gb2    = (const float*)d_in[16];
    float* out = (float*)d_out;

    char* ws = (char*)d_ws;
    size_t off = 0;
    auto alloc = [&](size_t bytes) -> void* {
        void* p = ws + off;
        off += (bytes + 255) & ~(size_t)255;
        return p;
    };
    float*    hbuf   = (float*)   alloc((size_t)NN * HH * 4);  // f32 h (51.2 MB)
    unsigned* tH     = (unsigned*)alloc((size_t)NN * 64 * 4);  // bf16x2 t (25.6 MB)
    float*    y1     = (float*)   alloc((size_t)NN * 64 * 4);  // node-head y1 (25.6 MB)
    int*      csr    = (int*)     alloc((size_t)EE * 4);       // 6.4 MB
    int*      offs   = (int*)     alloc((size_t)NN * 4);
    int*      cnt    = (int*)     alloc((size_t)NN * 4);
    int*      cursor = (int*)     alloc((size_t)NN * 4);
    float*    dinv   = (float*)   alloc((size_t)NN * 4);
    int*      blksum = (int*)     alloc((size_t)NBLK * 4);
    float*    bnA    = (float*)   alloc((size_t)LL * HH * 4);
    float*    bnB    = (float*)   alloc((size_t)LL * HH * 4);
    float*    gsum   = (float*)   alloc((size_t)GG * HH * 4);
    float*    gcnt   = (float*)   alloc((size_t)GG * 4);
    float*    cwT    = (float*)   alloc((size_t)LL * HH * HH * 4);
    float*    n1T    = (float*)   alloc((size_t)64 * HH * 4);
    int*      flag   = (int*)     alloc(256);

    // int-width detect + CSR build + dinv + folded BN + weight transpose
    k_idet<<<1, 256, 0, stream>>>(ei, flag);
    hipMemsetAsync(cnt, 0, (size_t)NN * 4, stream);
    k_count<<<(EE + 255) / 256, 256, 0, stream>>>(ei, cnt, flag);
    k_scan1<<<NBLK, SCAN_B, 0, stream>>>(cnt, offs, blksum);
    k_scan2<<<1, 256, 0, stream>>>(blksum);
    k_scan3<<<(NN + 255) / 256, 256, 0, stream>>>(cnt, offs, blksum, cursor,
            dinv, bnA, bnB, conv_b, bn_g, bn_b, bn_m, bn_v, gsum, gcnt);
    k_fill<<<(EE + 255) / 256, 256, 0, stream>>>(ei, cursor, csr, flag);
    k_prep<<<(LL * HH * HH + 255) / 256, 256, 0, stream>>>(conv_w, nw1, cwT, n1T);

    // 3 GCN layers: gemm(h -> bf16 t), fused aggregate+BN+ReLU (t -> f32 h)
    for (int l = 0; l < LL; l++) {
        const float* hin = (l == 0) ? x : hbuf;
        k_gemm<HH><<<(NN + 63) / 64, 256, 0, stream>>>(hin, cwT + (size_t)l * HH * HH,
                                                       nullptr, nullptr, tH, 0);
        k_aggr<<<(NN + 3) / 4, 256, 0, stream>>>(tH, csr, offs, cnt, dinv,
                                                 bnA + l * HH, bnB + l * HH, hbuf);
    }

    // node head: y1 = relu(h @ nw1^T + b1), then 64->2 reduce
    k_gemm<64><<<(NN + 63) / 64, 256, 0, stream>>>(hbuf, n1T, nb1, y1, nullptr, 1);
    k_nodey2<<<(NN + 3) / 4, 256, 0, stream>>>(y1, nw2, nb2, out);

    // graph head
    k_pool<<<(NN + PN - 1) / PN, 64, 0, stream>>>(hbuf, batch, gsum, gcnt, flag);
    k_ghead<<<GG, 64, 0, stream>>>(gsum, gcnt, gw1, gb1, gw2, gb2, out);
}

// Round 5
// 724.150 us; speedup vs baseline: 1.5763x; 1.4259x over previous
//
#include <hip/hip_runtime.h>
#include <hip/hip_bf16.h>

#define NN 100000
#define EE 1600000
#define HH 128
#define GG 64
#define LL 3
#define BN_EPS 1e-5f
#define SCAN_B 512
#define NBLK 196            // ceil(NN / SCAN_B)

typedef __hip_bfloat16 bf16;

__device__ __forceinline__ float lo16(unsigned v) { return __uint_as_float(v << 16); }
__device__ __forceinline__ float hi16(unsigned v) { return __uint_as_float(v & 0xffff0000u); }
__device__ __forceinline__ unsigned pack2(float a, float b) {
    bf16 ha = __float2bfloat16(a), hb = __float2bfloat16(b);
    unsigned short ua = *(unsigned short*)&ha, ub = *(unsigned short*)&hb;
    return (unsigned)ua | ((unsigned)ub << 16);
}

// ---- int64-vs-int32 detection: odd int32 slots all zero <=> int64 --------
__global__ __launch_bounds__(256) void k_idet(const int* __restrict__ ei,
                                              int* __restrict__ flag) {
    __shared__ int bad;
    if (threadIdx.x == 0) bad = 0;
    __syncthreads();
    int nz = 0;
    for (int j = 0; j < 16; j++) {
        int i = threadIdx.x * 16 + j;          // sample 4096 edges
        if (ei[2 * i + 1] != 0) nz = 1;
    }
    if (nz) atomicOr(&bad, 1);
    __syncthreads();
    if (threadIdx.x == 0) *flag = bad ? 0 : 1; // 1 = int64 layout
}

__device__ __forceinline__ int geti(const int* __restrict__ p, int i, int f) {
    return f ? p[2 * i] : p[i];
}

// ---- CSR build: count ----------------------------------------------------
__global__ void k_count(const int* __restrict__ ei, int* __restrict__ cnt,
                        const int* __restrict__ flag) {
    int e = blockIdx.x * 256 + threadIdx.x;
    int f = *flag;
    if (e < EE) atomicAdd(&cnt[geti(ei, EE + e, f)], 1);
}

// ---- scan pass 1: per-block inclusive scan -------------------------------
__global__ __launch_bounds__(SCAN_B) void k_scan1(const int* __restrict__ cnt,
        int* __restrict__ incl, int* __restrict__ blksum) {
    __shared__ int sd[SCAN_B];
    int t = threadIdx.x, i = blockIdx.x * SCAN_B + t;
    sd[t] = i < NN ? cnt[i] : 0;
    __syncthreads();
    for (int off = 1; off < SCAN_B; off <<= 1) {
        int y = t >= off ? sd[t - off] : 0;
        __syncthreads();
        sd[t] += y;
        __syncthreads();
    }
    if (i < NN) incl[i] = sd[t];
    if (t == SCAN_B - 1) blksum[blockIdx.x] = sd[t];
}

// ---- scan pass 2: scan the block sums (single block, in place) -----------
__global__ __launch_bounds__(256) void k_scan2(int* __restrict__ blksum) {
    __shared__ int sd[256];
    int t = threadIdx.x;
    sd[t] = t < NBLK ? blksum[t] : 0;
    __syncthreads();
    for (int off = 1; off < 256; off <<= 1) {
        int y = t >= off ? sd[t - off] : 0;
        __syncthreads();
        sd[t] += y;
        __syncthreads();
    }
    if (t < NBLK) blksum[t] = sd[t];
}

// ---- scan pass 3: offsets/cursor/dinv + folded BN + pool init ------------
__global__ void k_scan3(const int* __restrict__ cnt, int* __restrict__ offs,
        const int* __restrict__ blksum, int* __restrict__ cursor,
        float* __restrict__ dinv, float* __restrict__ bnA, float* __restrict__ bnB,
        const float* __restrict__ conv_b, const float* __restrict__ g,
        const float* __restrict__ be, const float* __restrict__ mn,
        const float* __restrict__ vr, float* __restrict__ gsum,
        float* __restrict__ gcnt) {
    int i = blockIdx.x * 256 + threadIdx.x;
    if (i < NN) {
        int b = i / SCAN_B;
        int add = b > 0 ? blksum[b - 1] : 0;
        int c = cnt[i];
        int ex = offs[i] + add - c;            // exclusive prefix
        offs[i] = ex;
        cursor[i] = ex;
        dinv[i] = rsqrtf(1.0f + (float)c);     // +1 = self loop
    }
    if (i < LL * HH) {
        float A = g[i] * rsqrtf(vr[i] + BN_EPS);
        bnA[i] = A;
        bnB[i] = (conv_b[i] - mn[i]) * A + be[i];
    }
    if (i < GG * HH) gsum[i] = 0.f;
    if (i < GG) gcnt[i] = 0.f;
}

// ---- CSR fill: counting sort by dst, pack {src, dinv[src]} ---------------
__global__ void k_fill(const int* __restrict__ ei, int* __restrict__ cursor,
                       uint2* __restrict__ ew, const float* __restrict__ dinv,
                       const int* __restrict__ flag) {
    int e = blockIdx.x * 256 + threadIdx.x;
    int f = *flag;
    if (e < EE) {
        int dst = geti(ei, EE + e, f);
        int src = geti(ei, e, f);
        int pos = atomicAdd(&cursor[dst], 1);
        ew[pos] = make_uint2((unsigned)src, __float_as_uint(dinv[src]));
    }
}

// ---- transpose weights: cwT[l][k][c] = conv_w[l][c][k]; n1T[k][c] --------
__global__ void k_prep(const float* __restrict__ conv_w,
                       const float* __restrict__ nw1,
                       float* __restrict__ cwT, float* __restrict__ n1T) {
    int i = blockIdx.x * 256 + threadIdx.x;
    if (i < LL * HH * HH) {
        int l = i >> 14, r = i & 16383;        // r = k*128 + c (dst layout)
        int k = r >> 7, c = r & 127;
        cwT[i] = conv_w[(l << 14) + c * HH + k];
    }
    if (i < 64 * HH) {                          // i = k*64 + c
        int k = i >> 6, c = i & 63;
        n1T[i] = nw1[c * HH + k];
    }
}

// ---- f32 tiled GEMM: out[r][c] = sum_k in[r][k] * Wt[k][c] (+bias,relu) --
// block = 256 thr, tile 64 rows x NC cols; input rows staged in LDS,
// read back as float4 (ds_read_b128, broadcast within lanes -> conflict-free)
template<int NC>
__global__ __launch_bounds__(256) void k_gemm(const float* __restrict__ in,
        const float* __restrict__ Wt, const float* __restrict__ bias,
        float* __restrict__ outF, unsigned* __restrict__ out2, int do_relu) {
    __shared__ float lin[64][HH];
    int t = threadIdx.x;
    int r0 = blockIdx.x * 64;
#pragma unroll
    for (int j = 0; j < 8; j++) {
        int fi = t + 256 * j;                  // float4 index 0..2047
        int row = fi >> 5, k4 = fi & 31;
        int gr = r0 + row;
        if (gr >= NN) gr = NN - 1;             // clamp (stores guarded)
        float4 v = ((const float4*)(in + (size_t)gr * HH))[k4];
        ((float4*)&lin[row][0])[k4] = v;
    }
    __syncthreads();
    constexpr int TX = NC / 4;                 // threads covering cols
    constexpr int RG = 64 / (256 / TX);        // rows per thread
    int tx = t % TX, ty = t / TX;
    int rbase = ty * RG;
    const float4* Wt4 = (const float4*)Wt;
    float4 acc[RG];
#pragma unroll
    for (int i = 0; i < RG; i++) acc[i] = make_float4(0.f, 0.f, 0.f, 0.f);
    for (int k4 = 0; k4 < HH / 4; k4++) {
        float4 w0 = Wt4[(4 * k4 + 0) * TX + tx];
        float4 w1 = Wt4[(4 * k4 + 1) * TX + tx];
        float4 w2 = Wt4[(4 * k4 + 2) * TX + tx];
        float4 w3 = Wt4[(4 * k4 + 3) * TX + tx];
#pragma unroll
        for (int i = 0; i < RG; i++) {
            float4 a = ((const float4*)&lin[rbase + i][0])[k4];
            acc[i].x = fmaf(a.x, w0.x, acc[i].x); acc[i].y = fmaf(a.x, w0.y, acc[i].y);
            acc[i].z = fmaf(a.x, w0.z, acc[i].z); acc[i].w = fmaf(a.x, w0.w, acc[i].w);
            acc[i].x = fmaf(a.y, w1.x, acc[i].x); acc[i].y = fmaf(a.y, w1.y, acc[i].y);
            acc[i].z = fmaf(a.y, w1.z, acc[i].z); acc[i].w = fmaf(a.y, w1.w, acc[i].w);
            acc[i].x = fmaf(a.z, w2.x, acc[i].x); acc[i].y = fmaf(a.z, w2.y, acc[i].y);
            acc[i].z = fmaf(a.z, w2.z, acc[i].z); acc[i].w = fmaf(a.z, w2.w, acc[i].w);
            acc[i].x = fmaf(a.w, w3.x, acc[i].x); acc[i].y = fmaf(a.w, w3.y, acc[i].y);
            acc[i].z = fmaf(a.w, w3.z, acc[i].z); acc[i].w = fmaf(a.w, w3.w, acc[i].w);
        }
    }
    float4 bv = bias ? ((const float4*)bias)[tx] : make_float4(0.f, 0.f, 0.f, 0.f);
#pragma unroll
    for (int i = 0; i < RG; i++) {
        int gr = r0 + rbase + i;
        if (gr < NN) {
            float4 v = acc[i];
            v.x += bv.x; v.y += bv.y; v.z += bv.z; v.w += bv.w;
            if (do_relu) {
                v.x = fmaxf(v.x, 0.f); v.y = fmaxf(v.y, 0.f);
                v.z = fmaxf(v.z, 0.f); v.w = fmaxf(v.w, 0.f);
            }
            if (outF) ((float4*)(outF + (size_t)gr * NC))[tx] = v;
            if (out2)
                ((uint2*)(out2 + (size_t)gr * (NC / 2)))[tx] =
                    make_uint2(pack2(v.x, v.y), pack2(v.z, v.w));
        }
    }
}

// ---- fused gather segment-reduce + self-loop + BN + ReLU -----------------
// one wave per node; lanes split 32/32 over 2 edges (uint2 = 4 ch/lane);
// wave-cooperative meta staging (1 coalesced load per 64 edges + shfl);
// 8 row-gathers in flight; cross-half shfl_xor(32) reduce.
__global__ __launch_bounds__(256) void k_aggr(const uint2* __restrict__ tH2,
        const uint2* __restrict__ ew, const int* __restrict__ offs,
        const int* __restrict__ cnt, const float* __restrict__ dinv,
        const float* __restrict__ bnA, const float* __restrict__ bnB,
        float* __restrict__ hout) {
    int wave = threadIdx.x >> 6, lane = threadIdx.x & 63;
    int node = blockIdx.x * 4 + wave;
    if (node >= NN) return;
    int base = offs[node], ne = cnt[node];
    float dd = dinv[node];
    int half = lane >> 5, li = lane & 31;
    // self term as weight-masked virtual edge (only half 0 contributes)
    uint2 sv = tH2[(size_t)node * 32 + li];
    float ws = half ? 0.f : dd;
    float4 acc;
    acc.x = lo16(sv.x) * ws; acc.y = hi16(sv.x) * ws;
    acc.z = lo16(sv.y) * ws; acc.w = hi16(sv.y) * ws;
    for (int k0 = 0; k0 < ne; k0 += 64) {
        int idx = k0 + lane;
        uint2 m = make_uint2(0u, 0u);          // w=0 for invalid lanes
        if (idx < ne) m = ew[base + idx];
        int c2 = ne - k0 < 64 ? ne - k0 : 64;
        for (int kk = 0; kk < c2; kk += 16) {
            uint2 vv[8]; float wj[8];
#pragma unroll
            for (int j = 0; j < 8; j++) {
                int e = kk + 2 * j + half;
                int s = __shfl((int)m.x, e);
                float w = __shfl(__uint_as_float(m.y), e);
                wj[j] = e < c2 ? w : 0.f;
                vv[j] = tH2[(size_t)s * 32 + li];
            }
#pragma unroll
            for (int j = 0; j < 8; j++) {
                acc.x = fmaf(lo16(vv[j].x), wj[j], acc.x);
                acc.y = fmaf(hi16(vv[j].x), wj[j], acc.y);
                acc.z = fmaf(lo16(vv[j].y), wj[j], acc.z);
                acc.w = fmaf(hi16(vv[j].y), wj[j], acc.w);
            }
        }
    }
    acc.x += __shfl_xor(acc.x, 32);
    acc.y += __shfl_xor(acc.y, 32);
    acc.z += __shfl_xor(acc.z, 32);
    acc.w += __shfl_xor(acc.w, 32);
    if (half == 0) {
        float4 Av = ((const float4*)bnA)[li];
        float4 Bv = ((const float4*)bnB)[li];
        float4 r;
        r.x = fmaxf(fmaf(acc.x * dd, Av.x, Bv.x), 0.f);
        r.y = fmaxf(fmaf(acc.y * dd, Av.y, Bv.y), 0.f);
        r.z = fmaxf(fmaf(acc.z * dd, Av.z, Bv.z), 0.f);
        r.w = fmaxf(fmaf(acc.w * dd, Av.w, Bv.w), 0.f);
        ((float4*)(hout + (size_t)node * HH))[li] = r;
    }
}

// ---- node head stage 2: y2 = y1 @ w2^T + b2 (64 -> 2) --------------------
__global__ __launch_bounds__(256) void k_nodey2(const float* __restrict__ y1,
        const float* __restrict__ w2, const float* __restrict__ b2v,
        float* __restrict__ out) {
    int wave = threadIdx.x >> 6, lane = threadIdx.x & 63;
    int node = blockIdx.x * 4 + wave;
    if (node >= NN) return;
    float y = y1[(size_t)node * 64 + lane];
    float v0 = y * w2[lane];
    float v1 = y * w2[64 + lane];
#pragma unroll
    for (int off = 32; off; off >>= 1) {
        v0 += __shfl_xor(v0, off);
        v1 += __shfl_xor(v1, off);
    }
    if (lane == 0) {
        out[(size_t)node * 2]     = v0 + b2v[0];
        out[(size_t)node * 2 + 1] = v1 + b2v[1];
    }
}

// ---- graph pooling: 1 wave per 32-node chunk, run-flush atomics ----------
#define PN 32
__global__ __launch_bounds__(64) void k_pool(const float* __restrict__ hb,
        const int* __restrict__ batch, float* __restrict__ gsum,
        float* __restrict__ gcnt, const int* __restrict__ flag) {
    int lane = threadIdx.x;
    int f = *flag;
    int s0 = blockIdx.x * PN;
    int e0 = s0 + PN < NN ? s0 + PN : NN;
    int cur = geti(batch, s0, f);
    float a0 = 0.f, a1 = 0.f, cn = 0.f;
    for (int n = s0; n < e0; n++) {
        int g = geti(batch, n, f);
        if (g != cur) {                        // wave-uniform branch
            atomicAdd(&gsum[cur * HH + 2 * lane], a0);
            atomicAdd(&gsum[cur * HH + 2 * lane + 1], a1);
            if (lane == 0) atomicAdd(&gcnt[cur], cn);
            a0 = a1 = cn = 0.f; cur = g;
        }
        float2 v = ((const float2*)(hb + (size_t)n * HH))[lane];
        a0 += v.x; a1 += v.y; cn += 1.f;
    }
    atomicAdd(&gsum[cur * HH + 2 * lane], a0);
    atomicAdd(&gsum[cur * HH + 2 * lane + 1], a1);
    if (lane == 0) atomicAdd(&gcnt[cur], cn);
}

// ---- graph head: one block per graph -------------------------------------
__global__ __launch_bounds__(64) void k_ghead(const float* __restrict__ gsum,
        const float* __restrict__ gcnt, const float* __restrict__ w1,
        const float* __restrict__ b1, const float* __restrict__ w2,
        const float* __restrict__ b2v, float* __restrict__ out) {
    __shared__ float emb[HH];
    int g = blockIdx.x, lane = threadIdx.x;
    float cn = gcnt[g];
    cn = cn > 1.f ? cn : 1.f;
    float inv = 1.f / cn;
    emb[lane] = gsum[g * HH + lane] * inv;
    emb[lane + 64] = gsum[g * HH + 64 + lane] * inv;
    __syncthreads();
    float acc = b1[lane];
    for (int k = 0; k < HH; k++) acc = fmaf(emb[k], w1[lane * HH + k], acc);
    float y = fmaxf(acc, 0.f);
    float v0 = y * w2[lane];
    float v1 = y * w2[64 + lane];
#pragma unroll
    for (int off = 32; off; off >>= 1) {
        v0 += __shfl_xor(v0, off);
        v1 += __shfl_xor(v1, off);
    }
    if (lane == 0) {
        out[(size_t)NN * 2 + g * 2]     = v0 + b2v[0];
        out[(size_t)NN * 2 + g * 2 + 1] = v1 + b2v[1];
    }
}

extern "C" void kernel_launch(void* const* d_in, const int* in_sizes, int n_in,
                              void* d_out, int out_size, void* d_ws, size_t ws_size,
                              hipStream_t stream) {
    const float* x      = (const float*)d_in[0];
    const int*   ei     = (const int*)d_in[1];
    const int*   batch  = (const int*)d_in[2];
    const float* conv_w = (const float*)d_in[3];
    const float* conv_b = (const float*)d_in[4];
    const float* bn_g   = (const float*)d_in[5];
    const float* bn_b   = (const float*)d_in[6];
    const float* bn_m   = (const float*)d_in[7];
    const float* bn_v   = (const float*)d_in[8];
    const float* nw1    = (const float*)d_in[9];
    const float* nb1    = (const float*)d_in[10];
    const float* nw2    = (const float*)d_in[11];
    const float* nb2    = (const float*)d_in[12];
    const float* gw1    = (const float*)d_in[13];
    const float* gb1    = (const float*)d_in[14];
    const float* gw2    = (const float*)d_in[15];
    const float* gb2    = (const float*)d_in[16];
    float* out = (float*)d_out;

    char* ws = (char*)d_ws;
    size_t off = 0;
    auto alloc = [&](size_t bytes) -> void* {
        void* p = ws + off;
        off += (bytes + 255) & ~(size_t)255;
        return p;
    };
    float*    hbuf   = (float*)   alloc((size_t)NN * HH * 4);  // f32 h (51.2 MB)
    unsigned* tH     = (unsigned*)alloc((size_t)NN * 64 * 4);  // bf16x2 t (25.6 MB)
    float*    y1     = (float*)   alloc((size_t)NN * 64 * 4);  // node-head y1 (25.6 MB)
    uint2*    ewb    = (uint2*)   alloc((size_t)EE * 8);       // {src, dinv[src]} (12.8 MB)
    int*      offs   = (int*)     alloc((size_t)NN * 4);
    int*      cnt    = (int*)     alloc((size_t)NN * 4);
    int*      cursor = (int*)     alloc((size_t)NN * 4);
    float*    dinv   = (float*)   alloc((size_t)NN * 4);
    int*      blksum = (int*)     alloc((size_t)NBLK * 4);
    float*    bnA    = (float*)   alloc((size_t)LL * HH * 4);
    float*    bnB    = (float*)   alloc((size_t)LL * HH * 4);
    float*    gsum   = (float*)   alloc((size_t)GG * HH * 4);
    float*    gcnt   = (float*)   alloc((size_t)GG * 4);
    float*    cwT    = (float*)   alloc((size_t)LL * HH * HH * 4);
    float*    n1T    = (float*)   alloc((size_t)64 * HH * 4);
    int*      flag   = (int*)     alloc(256);

    // int-width detect + CSR build + dinv + folded BN + weight transpose
    k_idet<<<1, 256, 0, stream>>>(ei, flag);
    hipMemsetAsync(cnt, 0, (size_t)NN * 4, stream);
    k_count<<<(EE + 255) / 256, 256, 0, stream>>>(ei, cnt, flag);
    k_scan1<<<NBLK, SCAN_B, 0, stream>>>(cnt, offs, blksum);
    k_scan2<<<1, 256, 0, stream>>>(blksum);
    k_scan3<<<(NN + 255) / 256, 256, 0, stream>>>(cnt, offs, blksum, cursor,
            dinv, bnA, bnB, conv_b, bn_g, bn_b, bn_m, bn_v, gsum, gcnt);
    k_fill<<<(EE + 255) / 256, 256, 0, stream>>>(ei, cursor, ewb, dinv, flag);
    k_prep<<<(LL * HH * HH + 255) / 256, 256, 0, stream>>>(conv_w, nw1, cwT, n1T);

    // 3 GCN layers: gemm(h -> bf16 t), fused aggregate+BN+ReLU (t -> f32 h)
    for (int l = 0; l < LL; l++) {
        const float* hin = (l == 0) ? x : hbuf;
        k_gemm<HH><<<(NN + 63) / 64, 256, 0, stream>>>(hin, cwT + (size_t)l * HH * HH,
                                                       nullptr, nullptr, tH, 0);
        k_aggr<<<(NN + 3) / 4, 256, 0, stream>>>((const uint2*)tH, ewb, offs, cnt,
                                                 dinv, bnA + l * HH, bnB + l * HH, hbuf);
    }

    // node head: y1 = relu(h @ nw1^T + b1), then 64->2 reduce
    k_gemm<64><<<(NN + 63) / 64, 256, 0, stream>>>(hbuf, n1T, nb1, y1, nullptr, 1);
    k_nodey2<<<(NN + 3) / 4, 256, 0, stream>>>(y1, nw2, nb2, out);

    // graph head
    k_pool<<<(NN + PN - 1) / PN, 64, 0, stream>>>(hbuf, batch, gsum, gcnt, flag);
    k_ghead<<<GG, 64, 0, stream>>>(gsum, gcnt, gw1, gb1, gw2, gb2, out);
}

// Round 6
// 560.664 us; speedup vs baseline: 2.0360x; 1.2916x over previous
//
#include <hip/hip_runtime.h>
#include <hip/hip_bf16.h>

#define NN 100000
#define EE 1600000
#define HH 128
#define GG 64
#define LL 3
#define BN_EPS 1e-5f
#define NT 196              // ceil(NN/512) tiles of 512 nodes
#define CSR_CAP 16384       // LDS staging capacity in k_csr (edges/tile)

typedef __hip_bfloat16 bf16;
typedef __attribute__((ext_vector_type(8))) short short8;
typedef __attribute__((ext_vector_type(4))) float floatx4;

__device__ __forceinline__ float lo16(unsigned v) { return __uint_as_float(v << 16); }
__device__ __forceinline__ float hi16(unsigned v) { return __uint_as_float(v & 0xffff0000u); }
__device__ __forceinline__ unsigned short f2b(float v) {
    bf16 h = __float2bfloat16(v);
    return *(unsigned short*)&h;
}
__device__ __forceinline__ unsigned pack2(float a, float b) {
    return (unsigned)f2b(a) | ((unsigned)f2b(b) << 16);
}

// ---- int64-vs-int32 detection: odd int32 slots all zero <=> int64 --------
__global__ __launch_bounds__(256) void k_idet(const int* __restrict__ ei,
                                              int* __restrict__ flag) {
    __shared__ int bad;
    if (threadIdx.x == 0) bad = 0;
    __syncthreads();
    int nz = 0;
    for (int j = 0; j < 16; j++) {
        int i = threadIdx.x * 16 + j;
        if (ei[2 * i + 1] != 0) nz = 1;
    }
    if (nz) atomicOr(&bad, 1);
    __syncthreads();
    if (threadIdx.x == 0) *flag = bad ? 0 : 1; // 1 = int64 layout
}

__device__ __forceinline__ int geti(const int* __restrict__ p, int i, int f) {
    return f ? p[2 * i] : p[i];
}

// ---- tile histogram: tcnt[tile] += #edges with dst>>9 == tile ------------
__global__ __launch_bounds__(256) void k_tcnt(const int* __restrict__ ei,
        int* __restrict__ tcnt, const int* __restrict__ flag) {
    __shared__ int h[NT];
    int t = threadIdx.x;
    for (int i = t; i < NT; i += 256) h[i] = 0;
    __syncthreads();
    int f = *flag;
    int e0 = blockIdx.x * 4096;
#pragma unroll
    for (int i = 0; i < 16; i++) {
        int e = e0 + i * 256 + t;
        if (e < EE) atomicAdd(&h[geti(ei, EE + e, f) >> 9], 1);
    }
    __syncthreads();
    for (int i = t; i < NT; i += 256)
        if (h[i]) atomicAdd(&tcnt[i], h[i]);
}

// ---- tile scan: tbase = exclusive prefix of tcnt; tcur = tbase -----------
__global__ __launch_bounds__(256) void k_tscan(const int* __restrict__ tcnt,
        int* __restrict__ tbase, int* __restrict__ tcur) {
    __shared__ int sd[256];
    int t = threadIdx.x;
    int own = t < NT ? tcnt[t] : 0;
    sd[t] = own;
    __syncthreads();
    for (int off = 1; off < 256; off <<= 1) {
        int y = t >= off ? sd[t - off] : 0;
        __syncthreads();
        sd[t] += y;
        __syncthreads();
    }
    if (t < NT) {
        int ex = sd[t] - own;
        tbase[t] = ex;
        tcur[t] = ex;
    }
}

// ---- misc: folded BN consts + pool-accumulator init ----------------------
__global__ void k_misc(float* __restrict__ bnA, float* __restrict__ bnB,
        const float* __restrict__ conv_b, const float* __restrict__ g,
        const float* __restrict__ be, const float* __restrict__ mn,
        const float* __restrict__ vr, float* __restrict__ gsum,
        float* __restrict__ gcnt) {
    int i = blockIdx.x * 256 + threadIdx.x;
    if (i < LL * HH) {
        float A = g[i] * rsqrtf(vr[i] + BN_EPS);
        bnA[i] = A;
        bnB[i] = (conv_b[i] - mn[i]) * A + be[i];
    }
    if (i < GG * HH) gsum[i] = 0.f;
    if (i < GG) gcnt[i] = 0.f;
}

// ---- partition: block-local counting sort by tile, run-flush to tmp ------
__global__ __launch_bounds__(256) void k_part(const int* __restrict__ ei,
        int* __restrict__ tcur, uint2* __restrict__ tmp,
        const int* __restrict__ flag) {
    __shared__ int lcnt[NT], lbase[NT], gbase[NT];
    __shared__ int sd[256];
    __shared__ uint2 sorted[4096];
    int t = threadIdx.x;
    int f = *flag;
    int e0 = blockIdx.x * 4096;
    int nume = EE - e0 < 4096 ? EE - e0 : 4096;
    for (int i = t; i < NT; i += 256) lcnt[i] = 0;
    __syncthreads();
    uint2 ed[16]; int myloc[16], mytile[16];
#pragma unroll
    for (int i = 0; i < 16; i++) {
        int li = i * 256 + t;
        if (li < nume) {
            int e = e0 + li;
            int src = geti(ei, e, f), dst = geti(ei, EE + e, f);
            ed[i] = make_uint2((unsigned)src, (unsigned)dst);
            mytile[i] = dst >> 9;
            myloc[i] = atomicAdd(&lcnt[mytile[i]], 1);
        }
    }
    __syncthreads();
    int own = t < NT ? lcnt[t] : 0;
    sd[t] = own;
    __syncthreads();
    for (int off = 1; off < 256; off <<= 1) {
        int y = t >= off ? sd[t - off] : 0;
        __syncthreads();
        sd[t] += y;
        __syncthreads();
    }
    if (t < NT) {
        lbase[t] = sd[t] - own;
        gbase[t] = own > 0 ? atomicAdd(&tcur[t], own) : 0;
    }
    __syncthreads();
#pragma unroll
    for (int i = 0; i < 16; i++) {
        int li = i * 256 + t;
        if (li < nume) sorted[lbase[mytile[i]] + myloc[i]] = ed[i];
    }
    __syncthreads();
    for (int idx = t; idx < nume; idx += 256) {
        uint2 e = sorted[idx];
        int tile = (int)(e.y >> 9);
        tmp[gbase[tile] + (idx - lbase[tile])] = e;
    }
}

// ---- per-tile CSR: counts, scan, offs/cnt/dinv, place src coalesced ------
__global__ __launch_bounds__(256) void k_csr(const uint2* __restrict__ tmp,
        const int* __restrict__ tcnt, const int* __restrict__ tbase,
        unsigned* __restrict__ csr, int* __restrict__ offs,
        int* __restrict__ cnt, float* __restrict__ dinv) {
    __shared__ int c512[512], sc[512];
    __shared__ unsigned outb[CSR_CAP];
    int T = blockIdx.x, t = threadIdx.x;
    int ne = tcnt[T], bs = tbase[T];
    c512[t] = 0; c512[t + 256] = 0;
    __syncthreads();
    for (int i = t; i < ne; i += 256)
        atomicAdd(&c512[tmp[bs + i].y & 511], 1);
    __syncthreads();
    sc[t] = c512[t]; sc[t + 256] = c512[t + 256];
    __syncthreads();
    for (int off = 1; off < 512; off <<= 1) {
        int a = t >= off ? sc[t - off] : 0;
        int b = t + 256 >= off ? sc[t + 256 - off] : 0;
        __syncthreads();
        sc[t] += a; sc[t + 256] += b;
        __syncthreads();
    }
#pragma unroll
    for (int s = 0; s < 2; s++) {
        int i = t + s * 256;
        int c = c512[i], ex = sc[i] - c;
        int node = T * 512 + i;
        if (node < NN) {
            cnt[node] = c;
            offs[node] = bs + ex;
            dinv[node] = rsqrtf(1.0f + (float)c);
        }
        sc[i] = ex;                            // becomes local cursor
    }
    __syncthreads();
    if (ne <= CSR_CAP) {
        for (int i = t; i < ne; i += 256) {
            uint2 e = tmp[bs + i];
            int p = atomicAdd(&sc[e.y & 511], 1);
            outb[p] = e.x;
        }
        __syncthreads();
        for (int i = t; i < ne; i += 256) csr[bs + i] = outb[i];
    } else {                                   // pathological fallback
        for (int i = t; i < ne; i += 256) {
            uint2 e = tmp[bs + i];
            int p = atomicAdd(&sc[e.y & 511], 1);
            csr[bs + p] = e.x;
        }
    }
}

// ---- pack edge meta: (src<<15) | (bf16(dinv[src]) & 0x7fff) --------------
__global__ void k_wpack(const unsigned* __restrict__ csr,
        const float* __restrict__ dinv, unsigned* __restrict__ ewp) {
    int e = blockIdx.x * 256 + threadIdx.x;
    if (e < EE) {
        unsigned s = csr[e];
        ewp[e] = (s << 15) | ((unsigned)f2b(dinv[s]) & 0x7fffu);
    }
}

// ---- weight cast f32 -> bf16 (native [c][k] layout = B-fragment rows) ----
__global__ void k_prep(const float* __restrict__ conv_w,
                       const float* __restrict__ nw1,
                       unsigned short* __restrict__ cwB,
                       unsigned short* __restrict__ n1B) {
    int i = blockIdx.x * 256 + threadIdx.x;
    if (i < LL * HH * HH) cwB[i] = f2b(conv_w[i]);
    if (i < 64 * HH) n1B[i] = f2b(nw1[i]);
}

// ---- MFMA bf16 GEMM: out[r][c] = sum_k in[r][k]*W[c][k] (+bias, relu) ----
// wave = 16 rows; A frags direct from global (16B/lane), layer-0 converts
// f32 in-register. Output packed bf16 row-major.
template<typename AT, int NC>
__global__ __launch_bounds__(256) void k_gemm(const AT* __restrict__ in,
        const unsigned short* __restrict__ Wb, const float* __restrict__ bias,
        unsigned short* __restrict__ outh, int do_relu) {
    int wave = threadIdx.x >> 6, lane = threadIdx.x & 63;
    int ln = lane & 15, q = lane >> 4;
    int r0 = blockIdx.x * 64 + wave * 16;
    int row = r0 + ln;
    int rr = row < NN ? row : NN - 1;          // clamp loads, guard stores
    short8 a[4];
    if constexpr (sizeof(AT) == 2) {
        const short8* ap = (const short8*)(in + (size_t)rr * HH);
#pragma unroll
        for (int kt = 0; kt < 4; kt++) a[kt] = ap[kt * 4 + q];
    } else {
        const float4* ap = (const float4*)(in + (size_t)rr * HH);
#pragma unroll
        for (int kt = 0; kt < 4; kt++) {
            float4 f0 = ap[(kt * 4 + q) * 2];
            float4 f1 = ap[(kt * 4 + q) * 2 + 1];
            a[kt][0] = (short)f2b(f0.x); a[kt][1] = (short)f2b(f0.y);
            a[kt][2] = (short)f2b(f0.z); a[kt][3] = (short)f2b(f0.w);
            a[kt][4] = (short)f2b(f1.x); a[kt][5] = (short)f2b(f1.y);
            a[kt][6] = (short)f2b(f1.z); a[kt][7] = (short)f2b(f1.w);
        }
    }
#pragma unroll
    for (int ct = 0; ct < NC / 16; ct++) {
        int c = ct * 16 + ln;
        const short8* bp = (const short8*)(Wb + (size_t)c * HH);
        floatx4 acc = {0.f, 0.f, 0.f, 0.f};
#pragma unroll
        for (int kt = 0; kt < 4; kt++) {
            short8 b = bp[kt * 4 + q];
            acc = __builtin_amdgcn_mfma_f32_16x16x32_bf16(a[kt], b, acc, 0, 0, 0);
        }
        float bv = bias ? bias[c] : 0.f;
#pragma unroll
        for (int reg = 0; reg < 4; reg++) {
            int orow = r0 + q * 4 + reg;       // C/D: col=lane&15, row=quad*4+reg
            if (orow < NN) {
                float v = acc[reg] + bv;
                if (do_relu) v = fmaxf(v, 0.f);
                outh[(size_t)orow * NC + c] = f2b(v);
            }
        }
    }
}

// ---- fused gather segment-reduce + self-loop + BN + ReLU -----------------
// one wave per node; lanes split 32/32 over 2 edges (uint2 = 4 ch/lane);
// 4B packed meta, shfl broadcast, 16 row-gathers in flight; bf16 h out.
__global__ __launch_bounds__(256) void k_aggr(const uint2* __restrict__ tH2,
        const unsigned* __restrict__ ewp, const int* __restrict__ offs,
        const int* __restrict__ cnt, const float* __restrict__ dinv,
        const float* __restrict__ bnA, const float* __restrict__ bnB,
        uint2* __restrict__ hout) {
    int wave = threadIdx.x >> 6, lane = threadIdx.x & 63;
    int node = blockIdx.x * 4 + wave;
    if (node >= NN) return;
    int base = offs[node], ne = cnt[node];
    float dd = dinv[node];
    int half = lane >> 5, li = lane & 31;
    uint2 sv = tH2[(size_t)node * 32 + li];
    float ws = half ? 0.f : dd;                // self = virtual edge, half 0
    float4 acc;
    acc.x = lo16(sv.x) * ws; acc.y = hi16(sv.x) * ws;
    acc.z = lo16(sv.y) * ws; acc.w = hi16(sv.y) * ws;
    for (int k0 = 0; k0 < ne; k0 += 64) {
        int idx = k0 + lane;
        unsigned m = idx < ne ? ewp[base + idx] : 0u;   // w=0 when invalid
        int c2 = ne - k0 < 64 ? ne - k0 : 64;
        for (int kk = 0; kk < c2; kk += 32) {
            uint2 vv[16]; float wj[16];
#pragma unroll
            for (int j = 0; j < 16; j++) {
                int e = kk + 2 * j + half;
                unsigned mm = (unsigned)__shfl((int)m, e);
                int s = (int)(mm >> 15);
                wj[j] = __uint_as_float((mm & 0x7fffu) << 16);
                vv[j] = tH2[(size_t)s * 32 + li];
            }
#pragma unroll
            for (int j = 0; j < 16; j++) {
                acc.x = fmaf(lo16(vv[j].x), wj[j], acc.x);
                acc.y = fmaf(hi16(vv[j].x), wj[j], acc.y);
                acc.z = fmaf(lo16(vv[j].y), wj[j], acc.z);
                acc.w = fmaf(hi16(vv[j].y), wj[j], acc.w);
            }
        }
    }
    acc.x += __shfl_xor(acc.x, 32);
    acc.y += __shfl_xor(acc.y, 32);
    acc.z += __shfl_xor(acc.z, 32);
    acc.w += __shfl_xor(acc.w, 32);
    if (half == 0) {
        float4 Av = ((const float4*)bnA)[li];
        float4 Bv = ((const float4*)bnB)[li];
        float r0 = fmaxf(fmaf(acc.x * dd, Av.x, Bv.x), 0.f);
        float r1 = fmaxf(fmaf(acc.y * dd, Av.y, Bv.y), 0.f);
        float r2 = fmaxf(fmaf(acc.z * dd, Av.z, Bv.z), 0.f);
        float r3 = fmaxf(fmaf(acc.w * dd, Av.w, Bv.w), 0.f);
        hout[(size_t)node * 32 + li] = make_uint2(pack2(r0, r1), pack2(r2, r3));
    }
}

// ---- node head stage 2: y2 = y1 @ w2^T + b2 (64 -> 2) --------------------
__global__ __launch_bounds__(256) void k_nodey2(const unsigned short* __restrict__ y1h,
        const float* __restrict__ w2, const float* __restrict__ b2v,
        float* __restrict__ out) {
    int wave = threadIdx.x >> 6, lane = threadIdx.x & 63;
    int node = blockIdx.x * 4 + wave;
    if (node >= NN) return;
    float y = __uint_as_float((unsigned)y1h[(size_t)node * 64 + lane] << 16);
    float v0 = y * w2[lane];
    float v1 = y * w2[64 + lane];
#pragma unroll
    for (int off = 32; off; off >>= 1) {
        v0 += __shfl_xor(v0, off);
        v1 += __shfl_xor(v1, off);
    }
    if (lane == 0) {
        out[(size_t)node * 2]     = v0 + b2v[0];
        out[(size_t)node * 2 + 1] = v1 + b2v[1];
    }
}

// ---- graph pooling: 1 wave per 32-node chunk, run-flush atomics ----------
#define PN 32
__global__ __launch_bounds__(64) void k_pool(const unsigned* __restrict__ hb,
        const int* __restrict__ batch, float* __restrict__ gsum,
        float* __restrict__ gcnt, const int* __restrict__ flag) {
    int lane = threadIdx.x;
    int f = *flag;
    int s0 = blockIdx.x * PN;
    int e0 = s0 + PN < NN ? s0 + PN : NN;
    int cur = geti(batch, s0, f);
    float a0 = 0.f, a1 = 0.f, cn = 0.f;
    for (int n = s0; n < e0; n++) {
        int g = geti(batch, n, f);
        if (g != cur) {                        // wave-uniform branch
            atomicAdd(&gsum[cur * HH + 2 * lane], a0);
            atomicAdd(&gsum[cur * HH + 2 * lane + 1], a1);
            if (lane == 0) atomicAdd(&gcnt[cur], cn);
            a0 = a1 = cn = 0.f; cur = g;
        }
        unsigned v = hb[(size_t)n * 64 + lane];
        a0 += lo16(v); a1 += hi16(v); cn += 1.f;
    }
    atomicAdd(&gsum[cur * HH + 2 * lane], a0);
    atomicAdd(&gsum[cur * HH + 2 * lane + 1], a1);
    if (lane == 0) atomicAdd(&gcnt[cur], cn);
}

// ---- graph head: one block per graph -------------------------------------
__global__ __launch_bounds__(64) void k_ghead(const float* __restrict__ gsum,
        const float* __restrict__ gcnt, const float* __restrict__ w1,
        const float* __restrict__ b1, const float* __restrict__ w2,
        const float* __restrict__ b2v, float* __restrict__ out) {
    __shared__ float emb[HH];
    int g = blockIdx.x, lane = threadIdx.x;
    float cn = gcnt[g];
    cn = cn > 1.f ? cn : 1.f;
    float inv = 1.f / cn;
    emb[lane] = gsum[g * HH + lane] * inv;
    emb[lane + 64] = gsum[g * HH + 64 + lane] * inv;
    __syncthreads();
    float acc = b1[lane];
    for (int k = 0; k < HH; k++) acc = fmaf(emb[k], w1[lane * HH + k], acc);
    float y = fmaxf(acc, 0.f);
    float v0 = y * w2[lane];
    float v1 = y * w2[64 + lane];
#pragma unroll
    for (int off = 32; off; off >>= 1) {
        v0 += __shfl_xor(v0, off);
        v1 += __shfl_xor(v1, off);
    }
    if (lane == 0) {
        out[(size_t)NN * 2 + g * 2]     = v0 + b2v[0];
        out[(size_t)NN * 2 + g * 2 + 1] = v1 + b2v[1];
    }
}

extern "C" void kernel_launch(void* const* d_in, const int* in_sizes, int n_in,
                              void* d_out, int out_size, void* d_ws, size_t ws_size,
                              hipStream_t stream) {
    const float* x      = (const float*)d_in[0];
    const int*   ei     = (const int*)d_in[1];
    const int*   batch  = (const int*)d_in[2];
    const float* conv_w = (const float*)d_in[3];
    const float* conv_b = (const float*)d_in[4];
    const float* bn_g   = (const float*)d_in[5];
    const float* bn_b   = (const float*)d_in[6];
    const float* bn_m   = (const float*)d_in[7];
    const float* bn_v   = (const float*)d_in[8];
    const float* nw1    = (const float*)d_in[9];
    const float* nb1    = (const float*)d_in[10];
    const float* nw2    = (const float*)d_in[11];
    const float* nb2    = (const float*)d_in[12];
    const float* gw1    = (const float*)d_in[13];
    const float* gb1    = (const float*)d_in[14];
    const float* gw2    = (const float*)d_in[15];
    const float* gb2    = (const float*)d_in[16];
    float* out = (float*)d_out;

    char* ws = (char*)d_ws;
    size_t off = 0;
    auto alloc = [&](size_t bytes) -> void* {
        void* p = ws + off;
        off += (bytes + 255) & ~(size_t)255;
        return p;
    };
    // ~91 MB total
    unsigned short* hb   = (unsigned short*)alloc((size_t)NN * HH * 2); // bf16 h
    unsigned short* tb   = (unsigned short*)alloc((size_t)NN * HH * 2); // bf16 t
    unsigned short* y1h  = (unsigned short*)alloc((size_t)NN * 64 * 2);
    uint2*    tmp    = (uint2*)   alloc((size_t)EE * 8);   // tile buckets
    unsigned* csr    = (unsigned*)alloc((size_t)EE * 4);
    unsigned* ewp    = (unsigned*)alloc((size_t)EE * 4);   // packed meta
    int*      offs   = (int*)     alloc((size_t)NN * 4);
    int*      cnt    = (int*)     alloc((size_t)NN * 4);
    float*    dinv   = (float*)   alloc((size_t)NN * 4);
    int*      tcnt   = (int*)     alloc((size_t)NT * 4);
    int*      tbase  = (int*)     alloc((size_t)NT * 4);
    int*      tcur   = (int*)     alloc((size_t)NT * 4);
    float*    bnA    = (float*)   alloc((size_t)LL * HH * 4);
    float*    bnB    = (float*)   alloc((size_t)LL * HH * 4);
    float*    gsum   = (float*)   alloc((size_t)GG * HH * 4);
    float*    gcnt   = (float*)   alloc((size_t)GG * 4);
    unsigned short* cwB = (unsigned short*)alloc((size_t)LL * HH * HH * 2);
    unsigned short* n1B = (unsigned short*)alloc((size_t)64 * HH * 2);
    int*      flag   = (int*)     alloc(256);

    // CSR build: tile histogram -> scan -> partition -> per-tile sort
    k_idet<<<1, 256, 0, stream>>>(ei, flag);
    hipMemsetAsync(tcnt, 0, (size_t)NT * 4, stream);
    k_tcnt<<<(EE + 4095) / 4096, 256, 0, stream>>>(ei, tcnt, flag);
    k_tscan<<<1, 256, 0, stream>>>(tcnt, tbase, tcur);
    k_misc<<<32, 256, 0, stream>>>(bnA, bnB, conv_b, bn_g, bn_b, bn_m, bn_v,
                                   gsum, gcnt);
    k_part<<<(EE + 4095) / 4096, 256, 0, stream>>>(ei, tcur, tmp, flag);
    k_csr<<<NT, 256, 0, stream>>>(tmp, tcnt, tbase, csr, offs, cnt, dinv);
    k_wpack<<<(EE + 255) / 256, 256, 0, stream>>>(csr, dinv, ewp);
    k_prep<<<(LL * HH * HH + 255) / 256, 256, 0, stream>>>(conv_w, nw1, cwB, n1B);

    // 3 GCN layers: MFMA gemm (h -> bf16 t), fused aggr+BN+ReLU (t -> bf16 h)
    k_gemm<float, HH><<<(NN + 63) / 64, 256, 0, stream>>>(x, cwB, nullptr, tb, 0);
    k_aggr<<<(NN + 3) / 4, 256, 0, stream>>>((const uint2*)tb, ewp, offs, cnt,
                                             dinv, bnA, bnB, (uint2*)hb);
    for (int l = 1; l < LL; l++) {
        k_gemm<unsigned short, HH><<<(NN + 63) / 64, 256, 0, stream>>>(
            hb, cwB + (size_t)l * HH * HH, nullptr, tb, 0);
        k_aggr<<<(NN + 3) / 4, 256, 0, stream>>>((const uint2*)tb, ewp, offs, cnt,
                                                 dinv, bnA + l * HH, bnB + l * HH,
                                                 (uint2*)hb);
    }

    // node head: y1 = relu(h @ nw1^T + b1) via MFMA, then 64->2 reduce
    k_gemm<unsigned short, 64><<<(NN + 63) / 64, 256, 0, stream>>>(hb, n1B, nb1,
                                                                   y1h, 1);
    k_nodey2<<<(NN + 3) / 4, 256, 0, stream>>>(y1h, nw2, nb2, out);

    // graph head
    k_pool<<<(NN + PN - 1) / PN, 64, 0, stream>>>((const unsigned*)hb, batch,
                                                  gsum, gcnt, flag);
    k_ghead<<<GG, 64, 0, stream>>>(gsum, gcnt, gw1, gb1, gw2, gb2, out);
}

// Round 7
// 509.446 us; speedup vs baseline: 2.2407x; 1.1005x over previous
//
#include <hip/hip_runtime.h>
#include <hip/hip_bf16.h>

#define NN 100000
#define EE 1600000
#define HH 128
#define GG 64
#define LL 3
#define BN_EPS 1e-5f
#define NT 196              // ceil(NN/512) tiles of 512 nodes
#define CSR_CAP 16384       // LDS staging capacity in k_csr (edges/tile)

typedef __hip_bfloat16 bf16;
typedef __attribute__((ext_vector_type(8))) short short8;
typedef __attribute__((ext_vector_type(4))) float floatx4;

__device__ __forceinline__ float lo16(unsigned v) { return __uint_as_float(v << 16); }
__device__ __forceinline__ float hi16(unsigned v) { return __uint_as_float(v & 0xffff0000u); }
__device__ __forceinline__ unsigned short f2b(float v) {
    bf16 h = __float2bfloat16(v);
    return *(unsigned short*)&h;
}
__device__ __forceinline__ unsigned pack2(float a, float b) {
    return (unsigned)f2b(a) | ((unsigned)f2b(b) << 16);
}
__device__ __forceinline__ int geti(const int* __restrict__ p, int i, int f) {
    return f ? p[2 * i] : p[i];
}

// ---- tile histogram (+ inline int-width detect; block 0 publishes flag) --
__global__ __launch_bounds__(256) void k_tcnt(const int* __restrict__ ei,
        int* __restrict__ tcnt, int* __restrict__ flag) {
    __shared__ int h[NT];
    int t = threadIdx.x;
    int e0 = blockIdx.x * 4096;
    // int64 layout <=> odd int32 slots of this chunk are all zero
    int probe = ei[2 * (e0 + (t & 63)) + 1];
    int f = __any(probe != 0) ? 0 : 1;
    if (blockIdx.x == 0 && t == 0) *flag = f;
    for (int i = t; i < NT; i += 256) h[i] = 0;
    __syncthreads();
#pragma unroll
    for (int i = 0; i < 16; i++) {
        int e = e0 + i * 256 + t;
        if (e < EE) atomicAdd(&h[geti(ei, EE + e, f) >> 9], 1);
    }
    __syncthreads();
    for (int i = t; i < NT; i += 256)
        if (h[i]) atomicAdd(&tcnt[i], h[i]);
}

// ---- tile scan: tbase = exclusive prefix of tcnt; tcur = tbase -----------
__global__ __launch_bounds__(256) void k_tscan(const int* __restrict__ tcnt,
        int* __restrict__ tbase, int* __restrict__ tcur) {
    __shared__ int sd[256];
    int t = threadIdx.x;
    int own = t < NT ? tcnt[t] : 0;
    sd[t] = own;
    __syncthreads();
    for (int off = 1; off < 256; off <<= 1) {
        int y = t >= off ? sd[t - off] : 0;
        __syncthreads();
        sd[t] += y;
        __syncthreads();
    }
    if (t < NT) {
        int ex = sd[t] - own;
        tbase[t] = ex;
        tcur[t] = ex;
    }
}

// ---- partition: block-local counting sort by tile, run-flush to tmp ------
__global__ __launch_bounds__(256) void k_part(const int* __restrict__ ei,
        int* __restrict__ tcur, uint2* __restrict__ tmp) {
    __shared__ int lcnt[NT], lbase[NT], gbase[NT];
    __shared__ int sd[256];
    __shared__ uint2 sorted[4096];
    int t = threadIdx.x;
    int e0 = blockIdx.x * 4096;
    int probe = ei[2 * (e0 + (t & 63)) + 1];
    int f = __any(probe != 0) ? 0 : 1;
    int nume = EE - e0 < 4096 ? EE - e0 : 4096;
    for (int i = t; i < NT; i += 256) lcnt[i] = 0;
    __syncthreads();
    uint2 ed[16]; int myloc[16], mytile[16];
#pragma unroll
    for (int i = 0; i < 16; i++) {
        int li = i * 256 + t;
        if (li < nume) {
            int e = e0 + li;
            int src = geti(ei, e, f), dst = geti(ei, EE + e, f);
            ed[i] = make_uint2((unsigned)src, (unsigned)dst);
            mytile[i] = dst >> 9;
            myloc[i] = atomicAdd(&lcnt[mytile[i]], 1);
        }
    }
    __syncthreads();
    int own = t < NT ? lcnt[t] : 0;
    sd[t] = own;
    __syncthreads();
    for (int off = 1; off < 256; off <<= 1) {
        int y = t >= off ? sd[t - off] : 0;
        __syncthreads();
        sd[t] += y;
        __syncthreads();
    }
    if (t < NT) {
        lbase[t] = sd[t] - own;
        gbase[t] = own > 0 ? atomicAdd(&tcur[t], own) : 0;
    }
    __syncthreads();
#pragma unroll
    for (int i = 0; i < 16; i++) {
        int li = i * 256 + t;
        if (li < nume) sorted[lbase[mytile[i]] + myloc[i]] = ed[i];
    }
    __syncthreads();
    for (int idx = t; idx < nume; idx += 256) {
        uint2 e = sorted[idx];
        int tile = (int)(e.y >> 9);
        tmp[gbase[tile] + (idx - lbase[tile])] = e;
    }
}

// ---- per-tile CSR: counts, scan, offs/cnt/dinv, place src coalesced ------
__global__ __launch_bounds__(256) void k_csr(const uint2* __restrict__ tmp,
        const int* __restrict__ tcnt, const int* __restrict__ tbase,
        unsigned* __restrict__ csr, int* __restrict__ offs,
        int* __restrict__ cnt, float* __restrict__ dinv) {
    __shared__ int c512[512], sc[512];
    __shared__ unsigned outb[CSR_CAP];
    int T = blockIdx.x, t = threadIdx.x;
    int ne = tcnt[T], bs = tbase[T];
    c512[t] = 0; c512[t + 256] = 0;
    __syncthreads();
    for (int i = t; i < ne; i += 256)
        atomicAdd(&c512[tmp[bs + i].y & 511], 1);
    __syncthreads();
    sc[t] = c512[t]; sc[t + 256] = c512[t + 256];
    __syncthreads();
    for (int off = 1; off < 512; off <<= 1) {
        int a = t >= off ? sc[t - off] : 0;
        int b = t + 256 >= off ? sc[t + 256 - off] : 0;
        __syncthreads();
        sc[t] += a; sc[t + 256] += b;
        __syncthreads();
    }
#pragma unroll
    for (int s = 0; s < 2; s++) {
        int i = t + s * 256;
        int c = c512[i], ex = sc[i] - c;
        int node = T * 512 + i;
        if (node < NN) {
            cnt[node] = c;
            offs[node] = bs + ex;
            dinv[node] = rsqrtf(1.0f + (float)c);
        }
        sc[i] = ex;                            // becomes local cursor
    }
    __syncthreads();
    if (ne <= CSR_CAP) {
        for (int i = t; i < ne; i += 256) {
            uint2 e = tmp[bs + i];
            int p = atomicAdd(&sc[e.y & 511], 1);
            outb[p] = e.x;
        }
        __syncthreads();
        for (int i = t; i < ne; i += 256) csr[bs + i] = outb[i];
    } else {                                   // pathological fallback
        for (int i = t; i < ne; i += 256) {
            uint2 e = tmp[bs + i];
            int p = atomicAdd(&sc[e.y & 511], 1);
            csr[bs + p] = e.x;
        }
    }
}

// ---- merged prep: edge-meta pack + weight casts + BN fold + pool init ----
__global__ void k_prep2(const unsigned* __restrict__ csr,
        const float* __restrict__ dinv, unsigned* __restrict__ ewp,
        const float* __restrict__ conv_w, const float* __restrict__ nw1,
        unsigned short* __restrict__ cwB, unsigned short* __restrict__ n1B,
        float* __restrict__ bnA, float* __restrict__ bnB,
        const float* __restrict__ conv_b, const float* __restrict__ g,
        const float* __restrict__ be, const float* __restrict__ mn,
        const float* __restrict__ vr, float* __restrict__ gsum,
        float* __restrict__ gcnt) {
    int i = blockIdx.x * 256 + threadIdx.x;
    if (i < EE) {
        unsigned s = csr[i];
        ewp[i] = (s << 15) | ((unsigned)f2b(dinv[s]) & 0x7fffu);
    }
    if (i < LL * HH * HH) cwB[i] = f2b(conv_w[i]);
    if (i < 64 * HH) n1B[i] = f2b(nw1[i]);
    if (i < LL * HH) {
        float A = g[i] * rsqrtf(vr[i] + BN_EPS);
        bnA[i] = A;
        bnB[i] = (conv_b[i] - mn[i]) * A + be[i];
    }
    if (i < GG * HH) gsum[i] = 0.f;
    if (i < GG) gcnt[i] = 0.f;
}

// ---- MFMA bf16 GEMM: out[r][c] = sum_k in[r][k]*W[c][k] (+bias, relu) ----
// FUSE: fold y2 = y1 @ w2^T + b2 (64->2) into the epilogue (node head).
template<typename AT, int NC, bool FUSE>
__global__ __launch_bounds__(256) void k_gemm(const AT* __restrict__ in,
        const unsigned short* __restrict__ Wb, const float* __restrict__ bias,
        unsigned short* __restrict__ outh, int do_relu,
        const float* __restrict__ w2, const float* __restrict__ b2v,
        float* __restrict__ out2f) {
    int wave = threadIdx.x >> 6, lane = threadIdx.x & 63;
    int ln = lane & 15, q = lane >> 4;
    int r0 = blockIdx.x * 64 + wave * 16;
    int row = r0 + ln;
    int rr = row < NN ? row : NN - 1;          // clamp loads, guard stores
    short8 a[4];
    if constexpr (sizeof(AT) == 2) {
        const short8* ap = (const short8*)(in + (size_t)rr * HH);
#pragma unroll
        for (int kt = 0; kt < 4; kt++) a[kt] = ap[kt * 4 + q];
    } else {
        const float4* ap = (const float4*)(in + (size_t)rr * HH);
#pragma unroll
        for (int kt = 0; kt < 4; kt++) {
            float4 f0 = ap[(kt * 4 + q) * 2];
            float4 f1 = ap[(kt * 4 + q) * 2 + 1];
            a[kt][0] = (short)f2b(f0.x); a[kt][1] = (short)f2b(f0.y);
            a[kt][2] = (short)f2b(f0.z); a[kt][3] = (short)f2b(f0.w);
            a[kt][4] = (short)f2b(f1.x); a[kt][5] = (short)f2b(f1.y);
            a[kt][6] = (short)f2b(f1.z); a[kt][7] = (short)f2b(f1.w);
        }
    }
    float p0[4], p1[4];
    if constexpr (FUSE) {
#pragma unroll
        for (int r = 0; r < 4; r++) { p0[r] = 0.f; p1[r] = 0.f; }
    }
#pragma unroll
    for (int ct = 0; ct < NC / 16; ct++) {
        int c = ct * 16 + ln;
        const short8* bp = (const short8*)(Wb + (size_t)c * HH);
        floatx4 acc = {0.f, 0.f, 0.f, 0.f};
#pragma unroll
        for (int kt = 0; kt < 4; kt++) {
            short8 b = bp[kt * 4 + q];
            acc = __builtin_amdgcn_mfma_f32_16x16x32_bf16(a[kt], b, acc, 0, 0, 0);
        }
        float bv = bias ? bias[c] : 0.f;
        if constexpr (FUSE) {
            float wa = w2[c], wb = w2[64 + c];
#pragma unroll
            for (int reg = 0; reg < 4; reg++) {
                float v = fmaxf(acc[reg] + bv, 0.f);   // y1 with bias+relu
                p0[reg] = fmaf(v, wa, p0[reg]);
                p1[reg] = fmaf(v, wb, p1[reg]);
            }
        } else {
#pragma unroll
            for (int reg = 0; reg < 4; reg++) {
                int orow = r0 + q * 4 + reg;   // C/D: col=lane&15, row=quad*4+reg
                if (orow < NN) {
                    float v = acc[reg] + bv;
                    if (do_relu) v = fmaxf(v, 0.f);
                    outh[(size_t)orow * NC + c] = f2b(v);
                }
            }
        }
    }
    if constexpr (FUSE) {
#pragma unroll
        for (int off = 1; off < 16; off <<= 1) {
#pragma unroll
            for (int r = 0; r < 4; r++) {
                p0[r] += __shfl_xor(p0[r], off);
                p1[r] += __shfl_xor(p1[r], off);
            }
        }
        if (ln == 0) {
            float ba = b2v[0], bb = b2v[1];
#pragma unroll
            for (int reg = 0; reg < 4; reg++) {
                int orow = r0 + q * 4 + reg;
                if (orow < NN)
                    ((float2*)out2f)[orow] = make_float2(p0[reg] + ba, p1[reg] + bb);
            }
        }
    }
}

// ---- fused gather segment-reduce + self-loop + BN + ReLU -----------------
// one wave per node; lanes split 32/32 over 2 edges (uint2 = 4 ch/lane);
// 4B packed meta, shfl broadcast, depth-8 pipeline; nontemporal bf16 h out.
__global__ __launch_bounds__(256) void k_aggr(const uint2* __restrict__ tH2,
        const unsigned* __restrict__ ewp, const int* __restrict__ offs,
        const int* __restrict__ cnt, const float* __restrict__ dinv,
        const float* __restrict__ bnA, const float* __restrict__ bnB,
        uint2* __restrict__ hout) {
    int wave = threadIdx.x >> 6, lane = threadIdx.x & 63;
    int node = blockIdx.x * 4 + wave;
    if (node >= NN) return;
    int base = offs[node], ne = cnt[node];
    float dd = dinv[node];
    int half = lane >> 5, li = lane & 31;
    uint2 sv = tH2[(size_t)node * 32 + li];
    float ws = half ? 0.f : dd;                // self = virtual edge, half 0
    float4 acc;
    acc.x = lo16(sv.x) * ws; acc.y = hi16(sv.x) * ws;
    acc.z = lo16(sv.y) * ws; acc.w = hi16(sv.y) * ws;
    for (int k0 = 0; k0 < ne; k0 += 64) {
        int idx = k0 + lane;
        unsigned m = idx < ne ? ewp[base + idx] : 0u;   // w=0 when invalid
        int c2 = ne - k0 < 64 ? ne - k0 : 64;
        for (int kk = 0; kk < c2; kk += 16) {
            uint2 vv[8]; float wj[8];
#pragma unroll
            for (int j = 0; j < 8; j++) {
                int e = kk + 2 * j + half;
                unsigned mm = (unsigned)__shfl((int)m, e);
                int s = (int)(mm >> 15);
                wj[j] = __uint_as_float((mm & 0x7fffu) << 16);
                vv[j] = tH2[(size_t)s * 32 + li];
            }
#pragma unroll
            for (int j = 0; j < 8; j++) {
                acc.x = fmaf(lo16(vv[j].x), wj[j], acc.x);
                acc.y = fmaf(hi16(vv[j].x), wj[j], acc.y);
                acc.z = fmaf(lo16(vv[j].y), wj[j], acc.z);
                acc.w = fmaf(hi16(vv[j].y), wj[j], acc.w);
            }
        }
    }
    acc.x += __shfl_xor(acc.x, 32);
    acc.y += __shfl_xor(acc.y, 32);
    acc.z += __shfl_xor(acc.z, 32);
    acc.w += __shfl_xor(acc.w, 32);
    if (half == 0) {
        float4 Av = ((const float4*)bnA)[li];
        float4 Bv = ((const float4*)bnB)[li];
        float r0 = fmaxf(fmaf(acc.x * dd, Av.x, Bv.x), 0.f);
        float r1 = fmaxf(fmaf(acc.y * dd, Av.y, Bv.y), 0.f);
        float r2 = fmaxf(fmaf(acc.z * dd, Av.z, Bv.z), 0.f);
        float r3 = fmaxf(fmaf(acc.w * dd, Av.w, Bv.w), 0.f);
        unsigned long long v64 =
            ((unsigned long long)pack2(r2, r3) << 32) | pack2(r0, r1);
        __builtin_nontemporal_store(v64,
            (unsigned long long*)&hout[(size_t)node * 32 + li]);
    }
}

// ---- graph pooling: 1 wave per 32-node chunk, run-flush atomics ----------
#define PN 32
__global__ __launch_bounds__(64) void k_pool(const unsigned* __restrict__ hb,
        const int* __restrict__ batch, float* __restrict__ gsum,
        float* __restrict__ gcnt, const int* __restrict__ flag) {
    int lane = threadIdx.x;
    int f = *flag;
    int s0 = blockIdx.x * PN;
    int e0 = s0 + PN < NN ? s0 + PN : NN;
    int cur = geti(batch, s0, f);
    float a0 = 0.f, a1 = 0.f, cn = 0.f;
    for (int n = s0; n < e0; n++) {
        int g = geti(batch, n, f);
        if (g != cur) {                        // wave-uniform branch
            atomicAdd(&gsum[cur * HH + 2 * lane], a0);
            atomicAdd(&gsum[cur * HH + 2 * lane + 1], a1);
            if (lane == 0) atomicAdd(&gcnt[cur], cn);
            a0 = a1 = cn = 0.f; cur = g;
        }
        unsigned v = hb[(size_t)n * 64 + lane];
        a0 += lo16(v); a1 += hi16(v); cn += 1.f;
    }
    atomicAdd(&gsum[cur * HH + 2 * lane], a0);
    atomicAdd(&gsum[cur * HH + 2 * lane + 1], a1);
    if (lane == 0) atomicAdd(&gcnt[cur], cn);
}

// ---- graph head: one block per graph -------------------------------------
__global__ __launch_bounds__(64) void k_ghead(const float* __restrict__ gsum,
        const float* __restrict__ gcnt, const float* __restrict__ w1,
        const float* __restrict__ b1, const float* __restrict__ w2,
        const float* __restrict__ b2v, float* __restrict__ out) {
    __shared__ float emb[HH];
    int g = blockIdx.x, lane = threadIdx.x;
    float cn = gcnt[g];
    cn = cn > 1.f ? cn : 1.f;
    float inv = 1.f / cn;
    emb[lane] = gsum[g * HH + lane] * inv;
    emb[lane + 64] = gsum[g * HH + 64 + lane] * inv;
    __syncthreads();
    float acc = b1[lane];
    for (int k = 0; k < HH; k++) acc = fmaf(emb[k], w1[lane * HH + k], acc);
    float y = fmaxf(acc, 0.f);
    float v0 = y * w2[lane];
    float v1 = y * w2[64 + lane];
#pragma unroll
    for (int off = 32; off; off >>= 1) {
        v0 += __shfl_xor(v0, off);
        v1 += __shfl_xor(v1, off);
    }
    if (lane == 0) {
        out[(size_t)NN * 2 + g * 2]     = v0 + b2v[0];
        out[(size_t)NN * 2 + g * 2 + 1] = v1 + b2v[1];
    }
}

extern "C" void kernel_launch(void* const* d_in, const int* in_sizes, int n_in,
                              void* d_out, int out_size, void* d_ws, size_t ws_size,
                              hipStream_t stream) {
    const float* x      = (const float*)d_in[0];
    const int*   ei     = (const int*)d_in[1];
    const int*   batch  = (const int*)d_in[2];
    const float* conv_w = (const float*)d_in[3];
    const float* conv_b = (const float*)d_in[4];
    const float* bn_g   = (const float*)d_in[5];
    const float* bn_b   = (const float*)d_in[6];
    const float* bn_m   = (const float*)d_in[7];
    const float* bn_v   = (const float*)d_in[8];
    const float* nw1    = (const float*)d_in[9];
    const float* nb1    = (const float*)d_in[10];
    const float* nw2    = (const float*)d_in[11];
    const float* nb2    = (const float*)d_in[12];
    const float* gw1    = (const float*)d_in[13];
    const float* gb1    = (const float*)d_in[14];
    const float* gw2    = (const float*)d_in[15];
    const float* gb2    = (const float*)d_in[16];
    float* out = (float*)d_out;

    char* ws = (char*)d_ws;
    size_t off = 0;
    auto alloc = [&](size_t bytes) -> void* {
        void* p = ws + off;
        off += (bytes + 255) & ~(size_t)255;
        return p;
    };
    unsigned short* hb   = (unsigned short*)alloc((size_t)NN * HH * 2); // bf16 h
    unsigned short* tb   = (unsigned short*)alloc((size_t)NN * HH * 2); // bf16 t
    uint2*    tmp    = (uint2*)   alloc((size_t)EE * 8);   // tile buckets
    unsigned* csr    = (unsigned*)alloc((size_t)EE * 4);
    unsigned* ewp    = (unsigned*)alloc((size_t)EE * 4);   // packed meta
    int*      offs   = (int*)     alloc((size_t)NN * 4);
    int*      cnt    = (int*)     alloc((size_t)NN * 4);
    float*    dinv   = (float*)   alloc((size_t)NN * 4);
    int*      tcnt   = (int*)     alloc((size_t)NT * 4);
    int*      tbase  = (int*)     alloc((size_t)NT * 4);
    int*      tcur   = (int*)     alloc((size_t)NT * 4);
    float*    bnA    = (float*)   alloc((size_t)LL * HH * 4);
    float*    bnB    = (float*)   alloc((size_t)LL * HH * 4);
    float*    gsum   = (float*)   alloc((size_t)GG * HH * 4);
    float*    gcnt   = (float*)   alloc((size_t)GG * 4);
    unsigned short* cwB = (unsigned short*)alloc((size_t)LL * HH * HH * 2);
    unsigned short* n1B = (unsigned short*)alloc((size_t)64 * HH * 2);
    int*      flag   = (int*)     alloc(256);

    // CSR build: histogram (+detect) -> scan -> partition -> per-tile sort
    hipMemsetAsync(tcnt, 0, (size_t)NT * 4, stream);
    k_tcnt<<<(EE + 4095) / 4096, 256, 0, stream>>>(ei, tcnt, flag);
    k_tscan<<<1, 256, 0, stream>>>(tcnt, tbase, tcur);
    k_part<<<(EE + 4095) / 4096, 256, 0, stream>>>(ei, tcur, tmp);
    k_csr<<<NT, 256, 0, stream>>>(tmp, tcnt, tbase, csr, offs, cnt, dinv);
    k_prep2<<<(EE + 255) / 256, 256, 0, stream>>>(csr, dinv, ewp, conv_w, nw1,
            cwB, n1B, bnA, bnB, conv_b, bn_g, bn_b, bn_m, bn_v, gsum, gcnt);

    // 3 GCN layers: MFMA gemm (h -> bf16 t), fused aggr+BN+ReLU (t -> bf16 h)
    k_gemm<float, HH, false><<<(NN + 63) / 64, 256, 0, stream>>>(
        x, cwB, nullptr, tb, 0, nullptr, nullptr, nullptr);
    k_aggr<<<(NN + 3) / 4, 256, 0, stream>>>((const uint2*)tb, ewp, offs, cnt,
                                             dinv, bnA, bnB, (uint2*)hb);
    for (int l = 1; l < LL; l++) {
        k_gemm<unsigned short, HH, false><<<(NN + 63) / 64, 256, 0, stream>>>(
            hb, cwB + (size_t)l * HH * HH, nullptr, tb, 0, nullptr, nullptr, nullptr);
        k_aggr<<<(NN + 3) / 4, 256, 0, stream>>>((const uint2*)tb, ewp, offs, cnt,
                                                 dinv, bnA + l * HH, bnB + l * HH,
                                                 (uint2*)hb);
    }

    // node head fully fused: y2 = relu(h@nw1^T+b1)@nw2^T+b2 in one kernel
    k_gemm<unsigned short, 64, true><<<(NN + 63) / 64, 256, 0, stream>>>(
        hb, n1B, nb1, nullptr, 1, nw2, nb2, out);

    // graph head
    k_pool<<<(NN + PN - 1) / PN, 64, 0, stream>>>((const unsigned*)hb, batch,
                                                  gsum, gcnt, flag);
    k_ghead<<<GG, 64, 0, stream>>>(gsum, gcnt, gw1, gb1, gw2, gb2, out);
}